// Round 11
// baseline (318.771 us; speedup 1.0000x reference)
//
#include <hip/hip_runtime.h>

typedef float f32x4 __attribute__((ext_vector_type(4)));
typedef float fvec4 __attribute__((ext_vector_type(4)));
typedef __bf16 bf16x8 __attribute__((ext_vector_type(8)));
typedef unsigned short u16;
typedef u16 u16x8 __attribute__((ext_vector_type(8)));
typedef u16 u16x4 __attribute__((ext_vector_type(4)));
typedef int i32x2 __attribute__((ext_vector_type(2)));

#define SCALE_Q 0.18257418583505536f   /* 30^-0.5 */
#define LOG2E   1.4426950408889634f
#define SCALE_Q2 (SCALE_Q * LOG2E)     /* folded: exp(s) = 2^(s*log2e) */

__device__ __forceinline__ u16 f2bf(float f) {
    union { __bf16 h; u16 u; } cv; cv.h = (__bf16)f; return cv.u;
}
__device__ __forceinline__ float bf2f(u16 u) {
    union { __bf16 h; u16 u; } cv; cv.u = u; return (float)cv.h;
}
__device__ __forceinline__ float exp2_raw(float x) {
    float r;
    asm("v_exp_f32 %0, %1" : "=v"(r) : "v"(x));
    return r;
}
__device__ __forceinline__ unsigned pk_bf16(float a, float b) {
    unsigned r;
    asm("v_cvt_pk_bf16_f32 %0, %1, %2" : "=v"(r) : "v"(a), "v"(b));
    return r;
}

// async global->LDS, 16B per lane; LDS dest = wave-uniform base + lane*16
#define GLD16(gsrc, ldst) __builtin_amdgcn_global_load_lds( \
    (const __attribute__((address_space(1))) unsigned*)(gsrc), \
    (__attribute__((address_space(3))) unsigned*)(ldst), 16, 0, 0)

// lane^16 cross-exchange pair
__device__ __forceinline__ void xswap16(int a, int b, int& u, int& v) {
#if __has_builtin(__builtin_amdgcn_permlane16_swap)
    i32x2 r = __builtin_amdgcn_permlane16_swap(a, b, false, false);
    u = r[0]; v = r[1];
#else
    int sa = __builtin_amdgcn_ds_swizzle(a, 0x401F);
    int sb = __builtin_amdgcn_ds_swizzle(b, 0x401F);
    bool hi = (threadIdx.x & 16) != 0;
    u = hi ? sb : a;
    v = hi ? b : sa;
#endif
}

// ---------------------------------------------------------------------------
// prep + ln1 merged (unchanged from r10)
// ---------------------------------------------------------------------------
__device__ __forceinline__ void border_yx(int i, int& y, int& x) {
    if (i < 1056)      { y = i / 264; x = i % 264; }
    else if (i < 2112) { int j = i - 1056; y = 260 + j / 264; x = j % 264; }
    else               { int j = i - 2112; y = 4 + (j >> 3); int xx = j & 7;
                         x = (xx < 4) ? xx : 256 + xx; }
}

__global__ __launch_bounds__(256)
void prepln_k(const float* __restrict__ x, const float* __restrict__ n1w,
              const float* __restrict__ n1b, u16* __restrict__ xn,
              const float* __restrict__ qkv_w, const float* __restrict__ proj_w,
              const float* __restrict__ fc1_w, const float* __restrict__ fc2_w,
              const int* __restrict__ rpi, const float* __restrict__ rpb,
              u16* __restrict__ qkvT, u16* __restrict__ projT,
              u16* __restrict__ fc1T, u16* __restrict__ fc2T,
              u16* __restrict__ bias5, unsigned* __restrict__ kp_u32,
              unsigned* __restrict__ vp_u32)
{
    if (blockIdx.x < 16384) {      // ----- LayerNorm1 -----
        int row = blockIdx.x * 4 + (threadIdx.x >> 6);
        int lane = threadIdx.x & 63;
        fvec4 v = {0.f, 0.f, 0.f, 0.f};
        if (lane < 45) v = *(const fvec4*)(x + (long)row * 180 + lane * 4);
        float s  = v.x + v.y + v.z + v.w;
        float sq = v.x * v.x + v.y * v.y + v.z * v.z + v.w * v.w;
        for (int m = 1; m < 64; m <<= 1) { s += __shfl_xor(s, m); sq += __shfl_xor(sq, m); }
        float mean = s * (1.f / 180.f);
        float var  = sq * (1.f / 180.f) - mean * mean;
        float rstd = rsqrtf(var + 1e-5f);
        if (lane < 45) {
            u16x4 o;
            #pragma unroll
            for (int j = 0; j < 4; j++) {
                int c = lane * 4 + j;
                o[j] = f2bf((v[j] - mean) * rstd * n1w[c] + n1b[c]);
            }
            *(u16x4*)(xn + (long)row * 192 + lane * 4) = o;
        } else if (lane < 48) {
            u16x4 z = {0, 0, 0, 0};
            *(u16x4*)(xn + (long)row * 192 + 180 + (lane - 45) * 4) = z;
        }
        return;
    }
    int idx = (blockIdx.x - 16384) * 256 + threadIdx.x;
    if (idx < 122880) {                        // qkvT[640][192]
        int col = idx / 192, k = idx % 192;
        qkvT[idx] = (col < 540 && k < 180) ? f2bf(qkv_w[k * 540 + col]) : (u16)0;
    } else if (idx < 172032) {                 // projT[256][192]
        int i = idx - 122880; int col = i / 192, k = i % 192;
        projT[i] = (col < 180 && k < 180) ? f2bf(proj_w[k * 180 + col]) : (u16)0;
    } else if (idx < 245760) {                 // fc1T[384][192]
        int i = idx - 172032; int col = i / 192, k = i % 192;
        fc1T[i] = (col < 360 && k < 180) ? f2bf(fc1_w[k * 360 + col]) : (u16)0;
    } else if (idx < 344064) {                 // fc2T[256][384]
        int i = idx - 245760; int col = i / 384, k = i % 384;
        fc2T[i] = (col < 180 && k < 360) ? f2bf(fc2_w[k * 180 + col]) : (u16)0;
    } else if (idx < 1228800) {                // bias5[(h*36+ch*4+mi)][lg][wv][l15][e]
        int i = idx - 344064;
        int e = i & 15, l15 = (i >> 4) & 15, wv2 = (i >> 8) & 3, lg2 = (i >> 10) & 3;
        int cm36 = i >> 12;
        int hh = cm36 / 36, cm = cm36 % 36;
        int ch = cm >> 2, mi = cm & 3;
        int ni = e >> 2, rr = e & 3;
        int q = wv2 * 64 + ni * 16 + l15;
        int key = ch * 64 + mi * 16 + lg2 * 4 + rr;
        bias5[i] = f2bf(rpb[rpi[q * 576 + key] * 6 + hh] * LOG2E);
    } else if (idx < 1628160) {                // K_pad border tokens (u32 x16)
        int i = idx - 1228800;
        int tok = i >> 4, wj = i & 15;
        int h = tok / 4160, b = tok % 4160, y, xx;
        border_yx(b, y, xx);
        kp_u32[((h * 264 + y) * 264 + xx) * 16 + wj] = 0u;
    } else if (idx < 2021376) {                // K_pad interior dims 30,31
        int i = idx - 1628160;
        int h = i / 65536, t = i % 65536;
        int y = t >> 8, xx = t & 255;
        kp_u32[((h * 264 + y + 4) * 264 + xx + 4) * 16 + 15] = 0u;
    } else if (idx < 2236800) {                // vP d=30 plane := 1.0
        int i = idx - 2021376;
        int h = i / 35904, r = i % 35904;
        vp_u32[(h * 32 + 30) * 35904 + r] = 0x3F803F80u;
    } else if (idx < 2452224) {                // vP d=31 plane := 0
        int i = idx - 2236800;
        int h = i / 35904, r = i % 35904;
        vp_u32[(h * 32 + 31) * 35904 + r] = 0u;
    } else if (idx < 3016704) {                // vP d<30 borders := 0
        int i = idx - 2452224;
        int hd = i / 3136, j = i % 3136;
        int h = hd / 30, d = hd % 30;
        int y, xu;
        if (j < 1088) { int r = j / 136; y = r + (r >= 4 ? 256 : 0); xu = j % 136; }
        else { int j2 = j - 1088; y = 4 + (j2 >> 3); int q = j2 & 7;
               xu = (q < 2) ? q : 128 + q; }
        vp_u32[((h * 32 + d) * 264 + y) * 136 + xu] = 0u;
    }
}

// ---------------------------------------------------------------------------
// LayerNorm over bf16 input (x2 residual stream) -> bf16 [row][192]
// ---------------------------------------------------------------------------
__global__ __launch_bounds__(256)
void lnb_k(const u16* __restrict__ in, const float* __restrict__ w,
           const float* __restrict__ b, u16* __restrict__ out)
{
    int row = blockIdx.x * 4 + (threadIdx.x >> 6);
    int lane = threadIdx.x & 63;
    fvec4 v = {0.f, 0.f, 0.f, 0.f};
    if (lane < 45) {
        u16x4 raw = *(const u16x4*)(in + (long)row * 192 + lane * 4);
        #pragma unroll
        for (int j = 0; j < 4; j++) v[j] = bf2f(raw[j]);
    }
    float s  = v.x + v.y + v.z + v.w;
    float sq = v.x * v.x + v.y * v.y + v.z * v.z + v.w * v.w;
    for (int m = 1; m < 64; m <<= 1) { s += __shfl_xor(s, m); sq += __shfl_xor(sq, m); }
    float mean = s * (1.f / 180.f);
    float var  = sq * (1.f / 180.f) - mean * mean;
    float rstd = rsqrtf(var + 1e-5f);
    if (lane < 45) {
        u16x4 o;
        #pragma unroll
        for (int j = 0; j < 4; j++) {
            int c = lane * 4 + j;
            o[j] = f2bf((v[j] - mean) * rstd * w[c] + b[c]);
        }
        *(u16x4*)(out + (long)row * 192 + lane * 4) = o;
    } else if (lane < 48) {
        u16x4 z = {0, 0, 0, 0};
        *(u16x4*)(out + (long)row * 192 + 180 + (lane - 45) * 4) = z;
    }
}

// ---------------------------------------------------------------------------
// V transpose -> planar vP[h][32][264][272] (unchanged from r10)
// ---------------------------------------------------------------------------
__global__ __launch_bounds__(256)
void vtr_k(const u16* __restrict__ v_s, u16* __restrict__ vP)
{
    __shared__ u16 tile[32][268];
    const int y = blockIdx.x, h = blockIdx.y;
    const int t = threadIdx.x;
    #pragma unroll
    for (int k2 = 0; k2 < 4; ++k2) {
        int u = t + k2 * 256;
        int x = u >> 2, dp = (u & 3) * 8;
        u16x8 v = *(const u16x8*)(v_s + (((long)(y * 256 + x)) * 6 + h) * 32 + dp);
        #pragma unroll
        for (int j = 0; j < 8; j++) tile[dp + j][x] = v[j];
    }
    __syncthreads();
    const long base = (((long)h * 32) * 264 + y + 4) * 272 + 4;
    #pragma unroll
    for (int k2 = 0; k2 < 4; ++k2) {
        int u = t + k2 * 256;
        if (u < 960) {
            int d = u >> 5, xg = u & 31;
            u16x4 a = *(const u16x4*)(&tile[d][xg * 8]);
            u16x4 b = *(const u16x4*)(&tile[d][xg * 8 + 4]);
            long dst = base + (long)d * (264 * 272) + xg * 8;
            *(u16x4*)(vP + dst) = a;
            *(u16x4*)(vP + dst + 4) = b;
        }
    }
}

// ---------------------------------------------------------------------------
// A-resident GEMM, 64-row panels (24KB LDS -> 6 blocks/CU) + z-split cols.
// Block: stage A panel once (per K-half), loop NCB 64-col blocks with B in
// registers (L2-hot), per-cb acc (reset each cb when NH==1; persistent
// acc[NCB] across the two K-halves when NH==2). 4 waves 2x2 over 64x64.
// EPI: 0=qkv scatter, 1=proj(+bias+f32 resid->bf16), 2=fc1 gelu->bf16,
//      3=fc2(+bias+bf16 resid->f32 out)
// ---------------------------------------------------------------------------
template<int KTOT, int NCB, int EPI>
__global__ __launch_bounds__(256)
void gemm_k(const u16* __restrict__ A, const u16* __restrict__ Bt,
            const float* __restrict__ bias, const float* __restrict__ resid,
            void* __restrict__ o0, void* __restrict__ o1, void* __restrict__ o2)
{
    constexpr int NH = KTOT / 192;             // K-halves (1 or 2)
    constexpr int AC = (NH == 1) ? 1 : NCB;
    __shared__ u16 lds_a[64 * 192];            // 24 KB
    const int tid = threadIdx.x;
    const int l = tid & 63, wv = tid >> 6;
    const int wm = wv >> 1, wn = wv & 1;
    const int l15 = l & 15, lg = l >> 4;
    const int rx7 = l15 & 7;
    const long rowb = (long)blockIdx.x * 64;
    const int cb0 = blockIdx.y * NCB;
    const f32x4 fz = {0.f, 0.f, 0.f, 0.f};

    f32x4 acc[AC][2][2];
    #pragma unroll
    for (int a2 = 0; a2 < AC; a2++)
        #pragma unroll
        for (int i = 0; i < 2; i++) { acc[a2][i][0] = fz; acc[a2][i][1] = fz; }

    const u16* aptr[2];
    #pragma unroll
    for (int mi = 0; mi < 2; mi++)
        aptr[mi] = lds_a + (wm * 32 + mi * 16 + l15) * 192;

    auto epilogue = [&](int cb, f32x4 (&ac)[2][2]) {
        #pragma unroll
        for (int nd = 0; nd < 2; nd++) {
            const int c = cb * 64 + wn * 32 + nd * 16 + l15;
            if (EPI == 0) {
                if (c < 540) {
                    const float bb = bias[c];
                    const int sec = (c >= 360) ? 2 : ((c >= 180) ? 1 : 0);
                    const int cc = c - sec * 180;
                    const int hh = cc / 30, d = cc - hh * 30;
                    #pragma unroll
                    for (int mi = 0; mi < 2; mi++) {
                        const long t0 = rowb + wm * 32 + mi * 16 + lg * 4;
                        const int y = (int)(t0 >> 8), x0 = (int)(t0 & 255);
                        if (sec == 0) {
                            int win = ((y >> 4) << 4) | (x0 >> 4);
                            int qrow0 = ((y & 15) << 4) | (x0 & 15);
                            u16* dst = (u16*)o0 + (((long)(win * 6 + hh)) * 256 + qrow0) * 32 + d;
                            #pragma unroll
                            for (int rr = 0; rr < 4; rr++)
                                dst[rr * 32] = f2bf((ac[mi][nd][rr] + bb) * SCALE_Q2);
                        } else if (sec == 1) {
                            u16* dst = (u16*)o1 + (((long)hh * 264 + y + 4) * 264 + x0 + 4) * 32 + d;
                            #pragma unroll
                            for (int rr = 0; rr < 4; rr++)
                                dst[rr * 32] = f2bf(ac[mi][nd][rr] + bb);
                        } else {
                            u16* dst = (u16*)o2 + (t0 * 6 + hh) * 32 + d;
                            #pragma unroll
                            for (int rr = 0; rr < 4; rr++)
                                dst[rr * 192] = f2bf(ac[mi][nd][rr] + bb);
                        }
                    }
                }
            } else if (EPI == 1) {
                if (c < 180) {
                    const float bb = bias[c];
                    #pragma unroll
                    for (int mi = 0; mi < 2; mi++) {
                        const long t0 = rowb + wm * 32 + mi * 16 + lg * 4;
                        const float* rs = resid + t0 * 180 + c;
                        u16* dst = (u16*)o0 + t0 * 192 + c;
                        #pragma unroll
                        for (int rr = 0; rr < 4; rr++)
                            dst[rr * 192] = f2bf(ac[mi][nd][rr] + bb + rs[rr * 180]);
                    }
                }
            } else if (EPI == 2) {
                const float bb = (c < 360) ? bias[c] : 0.f;
                #pragma unroll
                for (int mi = 0; mi < 2; mi++) {
                    const long t0 = rowb + wm * 32 + mi * 16 + lg * 4;
                    u16* dst = (u16*)o0 + t0 * 384 + c;
                    #pragma unroll
                    for (int rr = 0; rr < 4; rr++) {
                        float xx = ac[mi][nd][rr] + bb;
                        float u2n = -2.f * xx * (0.7978845608f + 0.0356774081f * xx * xx);
                        dst[rr * 384] = f2bf(xx / (1.f + __expf(u2n)));
                    }
                }
            } else {
                if (c < 180) {
                    const float bb = bias[c];
                    const u16* x2b = (const u16*)o1;
                    #pragma unroll
                    for (int mi = 0; mi < 2; mi++) {
                        const long t0 = rowb + wm * 32 + mi * 16 + lg * 4;
                        const u16* rs = x2b + t0 * 192 + c;
                        float* dst = (float*)o0 + t0 * 180 + c;
                        #pragma unroll
                        for (int rr = 0; rr < 4; rr++)
                            dst[rr * 180] = ac[mi][nd][rr] + bb + bf2f(rs[rr * 192]);
                    }
                }
            }
        }
    };

    #pragma unroll
    for (int hk = 0; hk < NH; ++hk) {
        if (hk) __syncthreads();               // waves done reading prev half
        #pragma unroll
        for (int R = 0; R < 6; ++R) {          // stage A: 64 rows x 24 granules
            int idx = R * 256 + tid;
            int row = idx / 24, gp = idx - row * 24;
            int g = (gp & 24) | ((gp & 7) ^ (row & 7));
            GLD16(A + (rowb + row) * KTOT + hk * 192 + g * 8,
                  (char*)lds_a + R * 4096 + wv * 1024);
        }
        __syncthreads();                       // A half ready (drains vmcnt)

        #pragma unroll
        for (int icb = 0; icb < NCB; ++icb) {
            f32x4 (&ac)[2][2] = acc[(NH == 1) ? 0 : icb];
            const u16* Bb = Bt + (long)((cb0 + icb) * 64 + wn * 32 + l15) * KTOT + hk * 192 + lg * 8;
            #pragma unroll
            for (int kg = 0; kg < 6; kg += 3) {
                bf16x8 bfr[2][3];
                #pragma unroll
                for (int g2 = 0; g2 < 3; ++g2) {
                    bfr[0][g2] = *(const bf16x8*)(Bb + (kg + g2) * 32);
                    bfr[1][g2] = *(const bf16x8*)(Bb + 16 * KTOT + (kg + g2) * 32);
                }
                #pragma unroll
                for (int g2 = 0; g2 < 3; ++g2) {
                    const int k = kg + g2;
                    const int gk = k * 4 + lg;
                    const int gpk = (gk & 24) | ((gk & 7) ^ rx7);
                    bf16x8 af[2];
                    #pragma unroll
                    for (int mi = 0; mi < 2; mi++)
                        af[mi] = *(const bf16x8*)(aptr[mi] + gpk * 8);
                    #pragma unroll
                    for (int mi = 0; mi < 2; mi++)
                        #pragma unroll
                        for (int nd = 0; nd < 2; nd++)
                            ac[mi][nd] = __builtin_amdgcn_mfma_f32_16x16x32_bf16(af[mi], bfr[nd][g2], ac[mi][nd], 0, 0, 0);
                }
            }
            if (NH == 1) {
                epilogue(cb0 + icb, ac);
                #pragma unroll
                for (int i = 0; i < 2; i++) { ac[i][0] = fz; ac[i][1] = fz; }
            }
        }
    }
    if (NH == 2) {
        #pragma unroll
        for (int icb = 0; icb < NCB; ++icb) epilogue(cb0 + icb, acc[icb]);
    }
}

// ---------------------------------------------------------------------------
// Attention (r10 core + bias register-prefetch one chunk ahead).
// ---------------------------------------------------------------------------
__global__ __launch_bounds__(256)
void attn_k(const u16* __restrict__ q_g, const u16* __restrict__ K_pad,
            const u16* __restrict__ vP, const u16* __restrict__ bias5,
            u16* __restrict__ attn_out)
{
    __shared__ u16 kc[2][64 * 32];
    __shared__ u16 vt[2][32 * 64];

    const int w = ((blockIdx.x & 7) << 5) | (blockIdx.x >> 3);   // XCD swizzle
    const int h = blockIdx.y;
    const int wy = w >> 4, wx = w & 15;
    const int tid = threadIdx.x;
    const int wv = tid >> 6, l = tid & 63;
    const int l15 = l & 15, lg = l >> 4;
    const int swzk = (l15 >> 1) & 3;
    const int swzv = l15 & 7;

    bf16x8 qb[4];
    #pragma unroll
    for (int ni = 0; ni < 4; ni++) {
        int qrow = wv * 64 + ni * 16 + l15;
        qb[ni] = *(const bf16x8*)(q_g + (((long)(w * 6 + h)) * 256 + qrow) * 32 + lg * 8);
    }

    f32x4 acc[2][4];
    #pragma unroll
    for (int i = 0; i < 2; i++)
        #pragma unroll
        for (int j = 0; j < 4; j++) acc[i][j] = (f32x4){0.f, 0.f, 0.f, 0.f};

    const int tK = tid >> 2;
    const int gtk = (l & 3) ^ ((l >> 3) & 3);
    const int aK = (tK >= 48) ? 2 : (tK >= 24 ? 1 : 0);
    const int bK = tK - aK * 24;
    const u16* KbaseRow = K_pad + (((long)(h * 264 + wy * 16)) * 264 + wx * 16) * 32 + gtk * 8;
    const int dV = tid >> 3;
    const int gtv = (l & 7) ^ (l >> 3);
    const int aV = gtv / 3, bV = (gtv % 3) * 8;
    const u16* Vrow0 = vP + ((((long)h * 32 + dV) * 264) + wy * 16) * 272 + wx * 16;
    const u16* Bp = bias5 + (long)h * 147456 + ((lg * 4 + wv) * 16 + l15) * 16;

    GLD16(KbaseRow + ((long)aK * 264 + bK) * 32, (char*)kc[0] + wv * 1024);
    GLD16(Vrow0 + aV * 272 + bV, (char*)vt[0] + wv * 1024);

    // bias for chunk 0 preloaded
    u16x8 bl[4], bh[4];
    #pragma unroll
    for (int mi = 0; mi < 4; mi++) {
        bl[mi] = *(const u16x8*)(Bp + mi * 4096);
        bh[mi] = *(const u16x8*)(Bp + mi * 4096 + 8);
    }

    #pragma unroll
    for (int ch = 0; ch < 9; ++ch) {
        __syncthreads();
        u16x8 bln[4], bhn[4];
        if (ch < 8) {   // prefetch chunk ch+1: K, V, bias
            int n = (ch + 1) * 64;
            int c1 = n / 24, c2 = n - c1 * 24;
            int bb2 = bK + c2;
            int t2 = bb2 >= 24;
            int oy = c1 + aK + t2, ox = bb2 - (t2 ? 24 : 0);
            GLD16(KbaseRow + ((long)oy * 264 + ox) * 32, (char*)kc[(ch + 1) & 1] + wv * 1024);
            int bbv = bV + c2;
            int t2v = bbv >= 24;
            int oyv = c1 + aV + t2v, oxv = bbv - (t2v ? 24 : 0);
            GLD16(Vrow0 + oyv * 272 + oxv, (char*)vt[(ch + 1) & 1] + wv * 1024);
            #pragma unroll
            for (int mi = 0; mi < 4; mi++) {
                bln[mi] = *(const u16x8*)(Bp + ((ch + 1) * 4 + mi) * 4096);
                bhn[mi] = *(const u16x8*)(Bp + ((ch + 1) * 4 + mi) * 4096 + 8);
            }
        }
        const u16* kcur = kc[ch & 1];
        const u16* vcur = vt[ch & 1];

        #pragma unroll
        for (int ks = 0; ks < 2; ++ks) {
            int Wp[2][4][2];
            #pragma unroll
            for (int mih = 0; mih < 2; ++mih) {
                int mi = ks * 2 + mih;
                int key = ks * 32 + mih * 16 + l15;
                bf16x8 ka = *(const bf16x8*)(kcur + key * 32 + (lg ^ swzk) * 8);
                union { u16x8 v; unsigned d[4]; } ulo, uhi;
                ulo.v = bl[mi]; uhi.v = bh[mi];
                f32x4 s[4];
                #pragma unroll
                for (int ni = 0; ni < 4; ni++) {
                    unsigned dA = (ni < 2) ? ulo.d[(ni & 1) * 2]     : uhi.d[(ni & 1) * 2];
                    unsigned dB = (ni < 2) ? ulo.d[(ni & 1) * 2 + 1] : uhi.d[(ni & 1) * 2 + 1];
                    f32x4 ci;
                    ci[0] = __uint_as_float(dA << 16);
                    ci[1] = __uint_as_float(dA & 0xFFFF0000u);
                    ci[2] = __uint_as_float(dB << 16);
                    ci[3] = __uint_as_float(dB & 0xFFFF0000u);
                    s[ni] = ci;
                }
                #pragma unroll
                for (int ni = 0; ni < 4; ni++)
                    s[ni] = __builtin_amdgcn_mfma_f32_16x16x32_bf16(ka, qb[ni], s[ni], 0, 0, 0);
                #pragma unroll
                for (int ni = 0; ni < 4; ni++) {
                    float p0 = exp2_raw(s[ni][0]);
                    float p1 = exp2_raw(s[ni][1]);
                    float p2 = exp2_raw(s[ni][2]);
                    float p3 = exp2_raw(s[ni][3]);
                    Wp[mih][ni][0] = (int)pk_bf16(p0, p1);
                    Wp[mih][ni][1] = (int)pk_bf16(p2, p3);
                }
            }
            bf16x8 va0 = *(const bf16x8*)(vcur + l15 * 64 + ((ks * 4 + lg) ^ swzv) * 8);
            bf16x8 va1 = *(const bf16x8*)(vcur + (16 + l15) * 64 + ((ks * 4 + lg) ^ swzv) * 8);
            #pragma unroll
            for (int ni = 0; ni < 4; ni++) {
                i32x2 r0 = __builtin_amdgcn_permlane32_swap(Wp[0][ni][0], Wp[1][ni][0], false, false);
                i32x2 r1 = __builtin_amdgcn_permlane32_swap(Wp[0][ni][1], Wp[1][ni][1], false, false);
                int wd0, wd1, wd2, wd3;
                xswap16(r0[0], r0[1], wd0, wd2);
                xswap16(r1[0], r1[1], wd1, wd3);
                union { int wd[4]; bf16x8 v; } pu;
                pu.wd[0] = wd0; pu.wd[1] = wd1; pu.wd[2] = wd2; pu.wd[3] = wd3;
                acc[0][ni] = __builtin_amdgcn_mfma_f32_16x16x32_bf16(va0, pu.v, acc[0][ni], 0, 0, 0);
                acc[1][ni] = __builtin_amdgcn_mfma_f32_16x16x32_bf16(va1, pu.v, acc[1][ni], 0, 0, 0);
            }
        }
        if (ch < 8) {
            #pragma unroll
            for (int mi = 0; mi < 4; mi++) { bl[mi] = bln[mi]; bh[mi] = bhn[mi]; }
        }
    }

    #pragma unroll
    for (int ni = 0; ni < 4; ni++) {
        float sum = __shfl(acc[1][ni][2], 48 + l15);
        float inv = 1.f / sum;
        int q = wv * 64 + ni * 16 + l15;
        int y = wy * 16 + (q >> 4), x = wx * 16 + (q & 15);
        u16* bp = attn_out + ((long)(y * 256 + x)) * 192 + h * 30;
        unsigned w0 = pk_bf16(acc[0][ni][0] * inv, acc[0][ni][1] * inv);
        unsigned w1 = pk_bf16(acc[0][ni][2] * inv, acc[0][ni][3] * inv);
        *(unsigned*)(bp + lg * 4)     = w0;
        *(unsigned*)(bp + lg * 4 + 2) = w1;
        unsigned w2 = pk_bf16(acc[1][ni][0] * inv, acc[1][ni][1] * inv);
        if (lg < 3) {
            unsigned w3 = pk_bf16(acc[1][ni][2] * inv, acc[1][ni][3] * inv);
            *(unsigned*)(bp + 16 + lg * 4)     = w2;
            *(unsigned*)(bp + 16 + lg * 4 + 2) = w3;
        } else {
            *(unsigned*)(bp + 28) = w2;
        }
    }
}

// ---------------------------------------------------------------------------
extern "C" void kernel_launch(void* const* d_in, const int* in_sizes, int n_in,
                              void* d_out, int out_size, void* d_ws, size_t ws_size,
                              hipStream_t stream)
{
    (void)in_sizes; (void)n_in; (void)out_size; (void)ws_size;
    const float* x      = (const float*)d_in[0];
    const int*   rpi    = (const int*)d_in[1];
    const float* n1w    = (const float*)d_in[2];
    const float* n1b    = (const float*)d_in[3];
    const float* qkv_w  = (const float*)d_in[4];
    const float* qkv_b  = (const float*)d_in[5];
    const float* rpb    = (const float*)d_in[6];
    const float* proj_w = (const float*)d_in[7];
    const float* proj_b = (const float*)d_in[8];
    const float* n2w    = (const float*)d_in[9];
    const float* n2b    = (const float*)d_in[10];
    const float* fc1_w  = (const float*)d_in[11];
    const float* fc1_b  = (const float*)d_in[12];
    const float* fc2_w  = (const float*)d_in[13];
    const float* fc2_b  = (const float*)d_in[14];
    float* out = (float*)d_out;

    char* ws = (char*)d_ws;
    size_t off = 0;
    auto alloc = [&](size_t bytes) -> void* {
        void* p = ws + off; off += (bytes + 511) & ~(size_t)511; return p;
    };
    u16*   xn     = (u16*)alloc(65536ull * 192 * 2);        // ln out; ao aliases
    u16*   q_g    = (u16*)alloc(65536ull * 192 * 2);        // [win][h][q][32]
    u16*   K_pad  = (u16*)alloc(6ull * 264 * 264 * 32 * 2); // [h][y][x][32]
    u16*   v_s    = (u16*)alloc(65536ull * 180 * 4);        // aliased with x2b
    u16*   x2b    = v_s;                                    // bf16 [t][192]
    u16*   vP     = (u16*)alloc(6ull * 32 * 264 * 272 * 2); // [h][d][y+4][x+4]
    u16*   bias5  = (u16*)alloc(6ull * 36 * 4 * 4 * 16 * 16 * 2);
    u16*   qkvT   = (u16*)alloc(640ull * 192 * 2);
    u16*   projT  = (u16*)alloc(256ull * 192 * 2);
    u16*   fc1T   = (u16*)alloc(384ull * 192 * 2);
    u16*   fc2T   = (u16*)alloc(256ull * 384 * 2);
    u16*   ao     = xn;    // ln1 zero-fills cols 180..191; attn fills 0..179
    u16*   h1     = q_g;   // fc1 out [t][384]: q_g+K_pad adjacent >= 50.3MB

    prepln_k<<<dim3(28168), dim3(256), 0, stream>>>(x, n1w, n1b, xn,
        qkv_w, proj_w, fc1_w, fc2_w, rpi, rpb,
        qkvT, projT, fc1T, fc2T, bias5, (unsigned*)K_pad, (unsigned*)vP);
    gemm_k<192, 3, 0><<<dim3(1024, 3), dim3(256), 0, stream>>>(
        xn, qkvT, qkv_b, (const float*)nullptr, q_g, K_pad, v_s);
    vtr_k<<<dim3(256, 6), dim3(256), 0, stream>>>(v_s, vP);
    attn_k<<<dim3(256, 6), dim3(256), 0, stream>>>(q_g, K_pad, vP, bias5, ao);
    gemm_k<192, 3, 1><<<dim3(1024, 1), dim3(256), 0, stream>>>(
        ao, projT, proj_b, x, x2b, nullptr, nullptr);
    lnb_k<<<dim3(16384), dim3(256), 0, stream>>>(x2b, n2w, n2b, xn);
    gemm_k<192, 3, 2><<<dim3(1024, 2), dim3(256), 0, stream>>>(
        xn, fc1T, fc1_b, (const float*)nullptr, h1, nullptr, nullptr);
    gemm_k<384, 3, 3><<<dim3(1024, 1), dim3(256), 0, stream>>>(
        h1, fc2T, fc2_b, (const float*)nullptr, out, x2b, nullptr);
}

// Round 12
// 268.401 us; speedup vs baseline: 1.1877x; 1.1877x over previous
//
#include <hip/hip_runtime.h>

typedef float f32x4 __attribute__((ext_vector_type(4)));
typedef float fvec4 __attribute__((ext_vector_type(4)));
typedef __bf16 bf16x8 __attribute__((ext_vector_type(8)));
typedef unsigned short u16;
typedef u16 u16x8 __attribute__((ext_vector_type(8)));
typedef u16 u16x4 __attribute__((ext_vector_type(4)));
typedef int i32x2 __attribute__((ext_vector_type(2)));

#define SCALE_Q 0.18257418583505536f   /* 30^-0.5 */
#define LOG2E   1.4426950408889634f
#define SCALE_Q2 (SCALE_Q * LOG2E)     /* folded: exp(s) = 2^(s*log2e) */

__device__ __forceinline__ u16 f2bf(float f) {
    union { __bf16 h; u16 u; } cv; cv.h = (__bf16)f; return cv.u;
}
__device__ __forceinline__ float bf2f(u16 u) {
    union { __bf16 h; u16 u; } cv; cv.u = u; return (float)cv.h;
}
__device__ __forceinline__ float exp2_raw(float x) {
    float r;
    asm("v_exp_f32 %0, %1" : "=v"(r) : "v"(x));
    return r;
}
__device__ __forceinline__ unsigned pk_bf16(float a, float b) {
    unsigned r;
    asm("v_cvt_pk_bf16_f32 %0, %1, %2" : "=v"(r) : "v"(a), "v"(b));
    return r;
}

// async global->LDS, 16B per lane; LDS dest = wave-uniform base + lane*16
#define GLD16(gsrc, ldst) __builtin_amdgcn_global_load_lds( \
    (const __attribute__((address_space(1))) unsigned*)(gsrc), \
    (__attribute__((address_space(3))) unsigned*)(ldst), 16, 0, 0)

// lane^16 cross-exchange pair
__device__ __forceinline__ void xswap16(int a, int b, int& u, int& v) {
#if __has_builtin(__builtin_amdgcn_permlane16_swap)
    i32x2 r = __builtin_amdgcn_permlane16_swap(a, b, false, false);
    u = r[0]; v = r[1];
#else
    int sa = __builtin_amdgcn_ds_swizzle(a, 0x401F);
    int sb = __builtin_amdgcn_ds_swizzle(b, 0x401F);
    bool hi = (threadIdx.x & 16) != 0;
    u = hi ? sb : a;
    v = hi ? b : sa;
#endif
}

// ---------------------------------------------------------------------------
// prep + ln1 merged (unchanged)
// ---------------------------------------------------------------------------
__device__ __forceinline__ void border_yx(int i, int& y, int& x) {
    if (i < 1056)      { y = i / 264; x = i % 264; }
    else if (i < 2112) { int j = i - 1056; y = 260 + j / 264; x = j % 264; }
    else               { int j = i - 2112; y = 4 + (j >> 3); int xx = j & 7;
                         x = (xx < 4) ? xx : 256 + xx; }
}

__global__ __launch_bounds__(256)
void prepln_k(const float* __restrict__ x, const float* __restrict__ n1w,
              const float* __restrict__ n1b, u16* __restrict__ xn,
              const float* __restrict__ qkv_w, const float* __restrict__ proj_w,
              const float* __restrict__ fc1_w, const float* __restrict__ fc2_w,
              const int* __restrict__ rpi, const float* __restrict__ rpb,
              u16* __restrict__ qkvT, u16* __restrict__ projT,
              u16* __restrict__ fc1T, u16* __restrict__ fc2T,
              u16* __restrict__ bias5, unsigned* __restrict__ kp_u32,
              unsigned* __restrict__ vp_u32)
{
    if (blockIdx.x < 16384) {      // ----- LayerNorm1 -----
        int row = blockIdx.x * 4 + (threadIdx.x >> 6);
        int lane = threadIdx.x & 63;
        fvec4 v = {0.f, 0.f, 0.f, 0.f};
        if (lane < 45) v = *(const fvec4*)(x + (long)row * 180 + lane * 4);
        float s  = v.x + v.y + v.z + v.w;
        float sq = v.x * v.x + v.y * v.y + v.z * v.z + v.w * v.w;
        for (int m = 1; m < 64; m <<= 1) { s += __shfl_xor(s, m); sq += __shfl_xor(sq, m); }
        float mean = s * (1.f / 180.f);
        float var  = sq * (1.f / 180.f) - mean * mean;
        float rstd = rsqrtf(var + 1e-5f);
        if (lane < 45) {
            u16x4 o;
            #pragma unroll
            for (int j = 0; j < 4; j++) {
                int c = lane * 4 + j;
                o[j] = f2bf((v[j] - mean) * rstd * n1w[c] + n1b[c]);
            }
            *(u16x4*)(xn + (long)row * 192 + lane * 4) = o;
        } else if (lane < 48) {
            u16x4 z = {0, 0, 0, 0};
            *(u16x4*)(xn + (long)row * 192 + 180 + (lane - 45) * 4) = z;
        }
        return;
    }
    int idx = (blockIdx.x - 16384) * 256 + threadIdx.x;
    if (idx < 122880) {                        // qkvT[640][192]
        int col = idx / 192, k = idx % 192;
        qkvT[idx] = (col < 540 && k < 180) ? f2bf(qkv_w[k * 540 + col]) : (u16)0;
    } else if (idx < 172032) {                 // projT[256][192]
        int i = idx - 122880; int col = i / 192, k = i % 192;
        projT[i] = (col < 180 && k < 180) ? f2bf(proj_w[k * 180 + col]) : (u16)0;
    } else if (idx < 245760) {                 // fc1T[384][192]
        int i = idx - 172032; int col = i / 192, k = i % 192;
        fc1T[i] = (col < 360 && k < 180) ? f2bf(fc1_w[k * 360 + col]) : (u16)0;
    } else if (idx < 344064) {                 // fc2T[256][384]
        int i = idx - 245760; int col = i / 384, k = i % 384;
        fc2T[i] = (col < 180 && k < 360) ? f2bf(fc2_w[k * 180 + col]) : (u16)0;
    } else if (idx < 1228800) {                // bias5[(h*36+ch*4+mi)][lg][wv][l15][e]
        int i = idx - 344064;
        int e = i & 15, l15 = (i >> 4) & 15, wv2 = (i >> 8) & 3, lg2 = (i >> 10) & 3;
        int cm36 = i >> 12;
        int hh = cm36 / 36, cm = cm36 % 36;
        int ch = cm >> 2, mi = cm & 3;
        int ni = e >> 2, rr = e & 3;
        int q = wv2 * 64 + ni * 16 + l15;
        int key = ch * 64 + mi * 16 + lg2 * 4 + rr;
        bias5[i] = f2bf(rpb[rpi[q * 576 + key] * 6 + hh] * LOG2E);
    } else if (idx < 1628160) {                // K_pad border tokens (u32 x16)
        int i = idx - 1228800;
        int tok = i >> 4, wj = i & 15;
        int h = tok / 4160, b = tok % 4160, y, xx;
        border_yx(b, y, xx);
        kp_u32[((h * 264 + y) * 264 + xx) * 16 + wj] = 0u;
    } else if (idx < 2021376) {                // K_pad interior dims 30,31
        int i = idx - 1628160;
        int h = i / 65536, t = i % 65536;
        int y = t >> 8, xx = t & 255;
        kp_u32[((h * 264 + y + 4) * 264 + xx + 4) * 16 + 15] = 0u;
    } else if (idx < 2236800) {                // vP d=30 plane := 1.0
        int i = idx - 2021376;
        int h = i / 35904, r = i % 35904;
        vp_u32[(h * 32 + 30) * 35904 + r] = 0x3F803F80u;
    } else if (idx < 2452224) {                // vP d=31 plane := 0
        int i = idx - 2236800;
        int h = i / 35904, r = i % 35904;
        vp_u32[(h * 32 + 31) * 35904 + r] = 0u;
    } else if (idx < 3016704) {                // vP d<30 borders := 0
        int i = idx - 2452224;
        int hd = i / 3136, j = i % 3136;
        int h = hd / 30, d = hd % 30;
        int y, xu;
        if (j < 1088) { int r = j / 136; y = r + (r >= 4 ? 256 : 0); xu = j % 136; }
        else { int j2 = j - 1088; y = 4 + (j2 >> 3); int q = j2 & 7;
               xu = (q < 2) ? q : 128 + q; }
        vp_u32[((h * 32 + d) * 264 + y) * 136 + xu] = 0u;
    }
}

// ---------------------------------------------------------------------------
// LayerNorm over bf16 input (x2 residual stream) -> bf16 [row][192]
// ---------------------------------------------------------------------------
__global__ __launch_bounds__(256)
void lnb_k(const u16* __restrict__ in, const float* __restrict__ w,
           const float* __restrict__ b, u16* __restrict__ out)
{
    int row = blockIdx.x * 4 + (threadIdx.x >> 6);
    int lane = threadIdx.x & 63;
    fvec4 v = {0.f, 0.f, 0.f, 0.f};
    if (lane < 45) {
        u16x4 raw = *(const u16x4*)(in + (long)row * 192 + lane * 4);
        #pragma unroll
        for (int j = 0; j < 4; j++) v[j] = bf2f(raw[j]);
    }
    float s  = v.x + v.y + v.z + v.w;
    float sq = v.x * v.x + v.y * v.y + v.z * v.z + v.w * v.w;
    for (int m = 1; m < 64; m <<= 1) { s += __shfl_xor(s, m); sq += __shfl_xor(sq, m); }
    float mean = s * (1.f / 180.f);
    float var  = sq * (1.f / 180.f) - mean * mean;
    float rstd = rsqrtf(var + 1e-5f);
    if (lane < 45) {
        u16x4 o;
        #pragma unroll
        for (int j = 0; j < 4; j++) {
            int c = lane * 4 + j;
            o[j] = f2bf((v[j] - mean) * rstd * w[c] + b[c]);
        }
        *(u16x4*)(out + (long)row * 192 + lane * 4) = o;
    } else if (lane < 48) {
        u16x4 z = {0, 0, 0, 0};
        *(u16x4*)(out + (long)row * 192 + 180 + (lane - 45) * 4) = z;
    }
}

// ---------------------------------------------------------------------------
// V transpose -> planar vP[h][32][264][272] (unchanged)
// ---------------------------------------------------------------------------
__global__ __launch_bounds__(256)
void vtr_k(const u16* __restrict__ v_s, u16* __restrict__ vP)
{
    __shared__ u16 tile[32][268];
    const int y = blockIdx.x, h = blockIdx.y;
    const int t = threadIdx.x;
    #pragma unroll
    for (int k2 = 0; k2 < 4; ++k2) {
        int u = t + k2 * 256;
        int x = u >> 2, dp = (u & 3) * 8;
        u16x8 v = *(const u16x8*)(v_s + (((long)(y * 256 + x)) * 6 + h) * 32 + dp);
        #pragma unroll
        for (int j = 0; j < 8; j++) tile[dp + j][x] = v[j];
    }
    __syncthreads();
    const long base = (((long)h * 32) * 264 + y + 4) * 272 + 4;
    #pragma unroll
    for (int k2 = 0; k2 < 4; ++k2) {
        int u = t + k2 * 256;
        if (u < 960) {
            int d = u >> 5, xg = u & 31;
            u16x4 a = *(const u16x4*)(&tile[d][xg * 8]);
            u16x4 b = *(const u16x4*)(&tile[d][xg * 8 + 4]);
            long dst = base + (long)d * (264 * 272) + xg * 8;
            *(u16x4*)(vP + dst) = a;
            *(u16x4*)(vP + dst + 4) = b;
        }
    }
}

// ---------------------------------------------------------------------------
// A-resident GEMM (r10 proven shape): 128-row panel, 48KB LDS, 4 waves 2x2,
// wave tile 64x32 (acc[4][2] -> 8 MFMA per 2 B-loads), PLUS blockIdx.y
// z-split of col-blocks (cb0) so the big GEMMs reach 3 resident blocks/CU.
// B in registers (L2-hot); per-cb acc reset when NH==1; persistent acc[NCB]
// across two K-halves when NH==2 (fc2).
// ---------------------------------------------------------------------------
template<int KTOT, int NCB, int EPI>
__global__ __launch_bounds__(256)
void gemm_k(const u16* __restrict__ A, const u16* __restrict__ Bt,
            const float* __restrict__ bias, const float* __restrict__ resid,
            void* __restrict__ o0, void* __restrict__ o1, void* __restrict__ o2)
{
    constexpr int NH = KTOT / 192;             // K-halves (1 or 2)
    constexpr int AC = (NH == 1) ? 1 : NCB;
    __shared__ u16 lds_a[128 * 192];           // 48 KB
    const int tid = threadIdx.x;
    const int l = tid & 63, wv = tid >> 6;
    const int wm = wv >> 1, wn = wv & 1;
    const int l15 = l & 15, lg = l >> 4;
    const int rx7 = l15 & 7;
    const long rowb = (long)blockIdx.x * 128;
    const int cb0 = blockIdx.y * NCB;
    const f32x4 fz = {0.f, 0.f, 0.f, 0.f};

    f32x4 acc[AC][4][2];
    #pragma unroll
    for (int a2 = 0; a2 < AC; a2++)
        #pragma unroll
        for (int i = 0; i < 4; i++) { acc[a2][i][0] = fz; acc[a2][i][1] = fz; }

    const u16* aptr[4];
    #pragma unroll
    for (int mi = 0; mi < 4; mi++)
        aptr[mi] = lds_a + (wm * 64 + mi * 16 + l15) * 192;

    auto epilogue = [&](int cb, f32x4 (&ac)[4][2]) {
        #pragma unroll
        for (int nd = 0; nd < 2; nd++) {
            const int c = cb * 64 + wn * 32 + nd * 16 + l15;
            if (EPI == 0) {
                if (c < 540) {
                    const float bb = bias[c];
                    const int sec = (c >= 360) ? 2 : ((c >= 180) ? 1 : 0);
                    const int cc = c - sec * 180;
                    const int hh = cc / 30, d = cc - hh * 30;
                    #pragma unroll
                    for (int mi = 0; mi < 4; mi++) {
                        const long t0 = rowb + wm * 64 + mi * 16 + lg * 4;
                        const int y = (int)(t0 >> 8), x0 = (int)(t0 & 255);
                        if (sec == 0) {
                            int win = ((y >> 4) << 4) | (x0 >> 4);
                            int qrow0 = ((y & 15) << 4) | (x0 & 15);
                            u16* dst = (u16*)o0 + (((long)(win * 6 + hh)) * 256 + qrow0) * 32 + d;
                            #pragma unroll
                            for (int rr = 0; rr < 4; rr++)
                                dst[rr * 32] = f2bf((ac[mi][nd][rr] + bb) * SCALE_Q2);
                        } else if (sec == 1) {
                            u16* dst = (u16*)o1 + (((long)hh * 264 + y + 4) * 264 + x0 + 4) * 32 + d;
                            #pragma unroll
                            for (int rr = 0; rr < 4; rr++)
                                dst[rr * 32] = f2bf(ac[mi][nd][rr] + bb);
                        } else {
                            u16* dst = (u16*)o2 + (t0 * 6 + hh) * 32 + d;
                            #pragma unroll
                            for (int rr = 0; rr < 4; rr++)
                                dst[rr * 192] = f2bf(ac[mi][nd][rr] + bb);
                        }
                    }
                }
            } else if (EPI == 1) {
                if (c < 180) {
                    const float bb = bias[c];
                    #pragma unroll
                    for (int mi = 0; mi < 4; mi++) {
                        const long t0 = rowb + wm * 64 + mi * 16 + lg * 4;
                        const float* rs = resid + t0 * 180 + c;
                        u16* dst = (u16*)o0 + t0 * 192 + c;
                        #pragma unroll
                        for (int rr = 0; rr < 4; rr++)
                            dst[rr * 192] = f2bf(ac[mi][nd][rr] + bb + rs[rr * 180]);
                    }
                }
            } else if (EPI == 2) {
                const float bb = (c < 360) ? bias[c] : 0.f;
                #pragma unroll
                for (int mi = 0; mi < 4; mi++) {
                    const long t0 = rowb + wm * 64 + mi * 16 + lg * 4;
                    u16* dst = (u16*)o0 + t0 * 384 + c;
                    #pragma unroll
                    for (int rr = 0; rr < 4; rr++) {
                        float xx = ac[mi][nd][rr] + bb;
                        float u2n = -2.f * xx * (0.7978845608f + 0.0356774081f * xx * xx);
                        dst[rr * 384] = f2bf(xx / (1.f + __expf(u2n)));
                    }
                }
            } else {
                if (c < 180) {
                    const float bb = bias[c];
                    const u16* x2b = (const u16*)o1;
                    #pragma unroll
                    for (int mi = 0; mi < 4; mi++) {
                        const long t0 = rowb + wm * 64 + mi * 16 + lg * 4;
                        const u16* rs = x2b + t0 * 192 + c;
                        float* dst = (float*)o0 + t0 * 180 + c;
                        #pragma unroll
                        for (int rr = 0; rr < 4; rr++)
                            dst[rr * 180] = ac[mi][nd][rr] + bb + bf2f(rs[rr * 192]);
                    }
                }
            }
        }
    };

    #pragma unroll
    for (int hk = 0; hk < NH; ++hk) {
        if (hk) __syncthreads();               // all waves done with prev half
        #pragma unroll
        for (int R = 0; R < 12; ++R) {         // stage A: 128 rows x 24 granules
            int idx = R * 256 + tid;
            int row = idx / 24, gp = idx - row * 24;
            int g = (gp & 24) | ((gp & 7) ^ (row & 7));
            GLD16(A + (rowb + row) * KTOT + hk * 192 + g * 8,
                  (char*)lds_a + R * 4096 + wv * 1024);
        }
        __syncthreads();                       // A half ready (drains vmcnt)

        #pragma unroll
        for (int icb = 0; icb < NCB; ++icb) {
            f32x4 (&ac)[4][2] = acc[(NH == 1) ? 0 : icb];
            const u16* Bb = Bt + (long)((cb0 + icb) * 64 + wn * 32 + l15) * KTOT + hk * 192 + lg * 8;
            #pragma unroll
            for (int kg = 0; kg < 6; kg += 3) {
                bf16x8 bfr[2][3];
                #pragma unroll
                for (int g2 = 0; g2 < 3; ++g2) {
                    bfr[0][g2] = *(const bf16x8*)(Bb + (kg + g2) * 32);
                    bfr[1][g2] = *(const bf16x8*)(Bb + 16 * KTOT + (kg + g2) * 32);
                }
                #pragma unroll
                for (int g2 = 0; g2 < 3; ++g2) {
                    const int k = kg + g2;
                    const int gk = k * 4 + lg;
                    const int gpk = (gk & 24) | ((gk & 7) ^ rx7);
                    bf16x8 af[4];
                    #pragma unroll
                    for (int mi = 0; mi < 4; mi++)
                        af[mi] = *(const bf16x8*)(aptr[mi] + gpk * 8);
                    #pragma unroll
                    for (int mi = 0; mi < 4; mi++)
                        #pragma unroll
                        for (int nd = 0; nd < 2; nd++)
                            ac[mi][nd] = __builtin_amdgcn_mfma_f32_16x16x32_bf16(af[mi], bfr[nd][g2], ac[mi][nd], 0, 0, 0);
                }
            }
            if (NH == 1) {
                epilogue(cb0 + icb, ac);
                #pragma unroll
                for (int i = 0; i < 4; i++) { ac[i][0] = fz; ac[i][1] = fz; }
            }
        }
    }
    if (NH == 2) {
        #pragma unroll
        for (int icb = 0; icb < NCB; ++icb) epilogue(cb0 + icb, acc[icb]);
    }
}

// ---------------------------------------------------------------------------
// Attention (r11: r10 core + bias register-prefetch one chunk ahead).
// ---------------------------------------------------------------------------
__global__ __launch_bounds__(256)
void attn_k(const u16* __restrict__ q_g, const u16* __restrict__ K_pad,
            const u16* __restrict__ vP, const u16* __restrict__ bias5,
            u16* __restrict__ attn_out)
{
    __shared__ u16 kc[2][64 * 32];
    __shared__ u16 vt[2][32 * 64];

    const int w = ((blockIdx.x & 7) << 5) | (blockIdx.x >> 3);   // XCD swizzle
    const int h = blockIdx.y;
    const int wy = w >> 4, wx = w & 15;
    const int tid = threadIdx.x;
    const int wv = tid >> 6, l = tid & 63;
    const int l15 = l & 15, lg = l >> 4;
    const int swzk = (l15 >> 1) & 3;
    const int swzv = l15 & 7;

    bf16x8 qb[4];
    #pragma unroll
    for (int ni = 0; ni < 4; ni++) {
        int qrow = wv * 64 + ni * 16 + l15;
        qb[ni] = *(const bf16x8*)(q_g + (((long)(w * 6 + h)) * 256 + qrow) * 32 + lg * 8);
    }

    f32x4 acc[2][4];
    #pragma unroll
    for (int i = 0; i < 2; i++)
        #pragma unroll
        for (int j = 0; j < 4; j++) acc[i][j] = (f32x4){0.f, 0.f, 0.f, 0.f};

    const int tK = tid >> 2;
    const int gtk = (l & 3) ^ ((l >> 3) & 3);
    const int aK = (tK >= 48) ? 2 : (tK >= 24 ? 1 : 0);
    const int bK = tK - aK * 24;
    const u16* KbaseRow = K_pad + (((long)(h * 264 + wy * 16)) * 264 + wx * 16) * 32 + gtk * 8;
    const int dV = tid >> 3;
    const int gtv = (l & 7) ^ (l >> 3);
    const int aV = gtv / 3, bV = (gtv % 3) * 8;
    const u16* Vrow0 = vP + ((((long)h * 32 + dV) * 264) + wy * 16) * 272 + wx * 16;
    const u16* Bp = bias5 + (long)h * 147456 + ((lg * 4 + wv) * 16 + l15) * 16;

    GLD16(KbaseRow + ((long)aK * 264 + bK) * 32, (char*)kc[0] + wv * 1024);
    GLD16(Vrow0 + aV * 272 + bV, (char*)vt[0] + wv * 1024);

    u16x8 bl[4], bh[4];
    #pragma unroll
    for (int mi = 0; mi < 4; mi++) {
        bl[mi] = *(const u16x8*)(Bp + mi * 4096);
        bh[mi] = *(const u16x8*)(Bp + mi * 4096 + 8);
    }

    #pragma unroll
    for (int ch = 0; ch < 9; ++ch) {
        __syncthreads();
        u16x8 bln[4], bhn[4];
        if (ch < 8) {   // prefetch chunk ch+1: K, V, bias
            int n = (ch + 1) * 64;
            int c1 = n / 24, c2 = n - c1 * 24;
            int bb2 = bK + c2;
            int t2 = bb2 >= 24;
            int oy = c1 + aK + t2, ox = bb2 - (t2 ? 24 : 0);
            GLD16(KbaseRow + ((long)oy * 264 + ox) * 32, (char*)kc[(ch + 1) & 1] + wv * 1024);
            int bbv = bV + c2;
            int t2v = bbv >= 24;
            int oyv = c1 + aV + t2v, oxv = bbv - (t2v ? 24 : 0);
            GLD16(Vrow0 + oyv * 272 + oxv, (char*)vt[(ch + 1) & 1] + wv * 1024);
            #pragma unroll
            for (int mi = 0; mi < 4; mi++) {
                bln[mi] = *(const u16x8*)(Bp + ((ch + 1) * 4 + mi) * 4096);
                bhn[mi] = *(const u16x8*)(Bp + ((ch + 1) * 4 + mi) * 4096 + 8);
            }
        }
        const u16* kcur = kc[ch & 1];
        const u16* vcur = vt[ch & 1];

        #pragma unroll
        for (int ks = 0; ks < 2; ++ks) {
            int Wp[2][4][2];
            #pragma unroll
            for (int mih = 0; mih < 2; ++mih) {
                int mi = ks * 2 + mih;
                int key = ks * 32 + mih * 16 + l15;
                bf16x8 ka = *(const bf16x8*)(kcur + key * 32 + (lg ^ swzk) * 8);
                union { u16x8 v; unsigned d[4]; } ulo, uhi;
                ulo.v = bl[mi]; uhi.v = bh[mi];
                f32x4 s[4];
                #pragma unroll
                for (int ni = 0; ni < 4; ni++) {
                    unsigned dA = (ni < 2) ? ulo.d[(ni & 1) * 2]     : uhi.d[(ni & 1) * 2];
                    unsigned dB = (ni < 2) ? ulo.d[(ni & 1) * 2 + 1] : uhi.d[(ni & 1) * 2 + 1];
                    f32x4 ci;
                    ci[0] = __uint_as_float(dA << 16);
                    ci[1] = __uint_as_float(dA & 0xFFFF0000u);
                    ci[2] = __uint_as_float(dB << 16);
                    ci[3] = __uint_as_float(dB & 0xFFFF0000u);
                    s[ni] = ci;
                }
                #pragma unroll
                for (int ni = 0; ni < 4; ni++)
                    s[ni] = __builtin_amdgcn_mfma_f32_16x16x32_bf16(ka, qb[ni], s[ni], 0, 0, 0);
                #pragma unroll
                for (int ni = 0; ni < 4; ni++) {
                    float p0 = exp2_raw(s[ni][0]);
                    float p1 = exp2_raw(s[ni][1]);
                    float p2 = exp2_raw(s[ni][2]);
                    float p3 = exp2_raw(s[ni][3]);
                    Wp[mih][ni][0] = (int)pk_bf16(p0, p1);
                    Wp[mih][ni][1] = (int)pk_bf16(p2, p3);
                }
            }
            bf16x8 va0 = *(const bf16x8*)(vcur + l15 * 64 + ((ks * 4 + lg) ^ swzv) * 8);
            bf16x8 va1 = *(const bf16x8*)(vcur + (16 + l15) * 64 + ((ks * 4 + lg) ^ swzv) * 8);
            #pragma unroll
            for (int ni = 0; ni < 4; ni++) {
                i32x2 r0 = __builtin_amdgcn_permlane32_swap(Wp[0][ni][0], Wp[1][ni][0], false, false);
                i32x2 r1 = __builtin_amdgcn_permlane32_swap(Wp[0][ni][1], Wp[1][ni][1], false, false);
                int wd0, wd1, wd2, wd3;
                xswap16(r0[0], r0[1], wd0, wd2);
                xswap16(r1[0], r1[1], wd1, wd3);
                union { int wd[4]; bf16x8 v; } pu;
                pu.wd[0] = wd0; pu.wd[1] = wd1; pu.wd[2] = wd2; pu.wd[3] = wd3;
                acc[0][ni] = __builtin_amdgcn_mfma_f32_16x16x32_bf16(va0, pu.v, acc[0][ni], 0, 0, 0);
                acc[1][ni] = __builtin_amdgcn_mfma_f32_16x16x32_bf16(va1, pu.v, acc[1][ni], 0, 0, 0);
            }
        }
        if (ch < 8) {
            #pragma unroll
            for (int mi = 0; mi < 4; mi++) { bl[mi] = bln[mi]; bh[mi] = bhn[mi]; }
        }
    }

    #pragma unroll
    for (int ni = 0; ni < 4; ni++) {
        float sum = __shfl(acc[1][ni][2], 48 + l15);
        float inv = 1.f / sum;
        int q = wv * 64 + ni * 16 + l15;
        int y = wy * 16 + (q >> 4), x = wx * 16 + (q & 15);
        u16* bp = attn_out + ((long)(y * 256 + x)) * 192 + h * 30;
        unsigned w0 = pk_bf16(acc[0][ni][0] * inv, acc[0][ni][1] * inv);
        unsigned w1 = pk_bf16(acc[0][ni][2] * inv, acc[0][ni][3] * inv);
        *(unsigned*)(bp + lg * 4)     = w0;
        *(unsigned*)(bp + lg * 4 + 2) = w1;
        unsigned w2 = pk_bf16(acc[1][ni][0] * inv, acc[1][ni][1] * inv);
        if (lg < 3) {
            unsigned w3 = pk_bf16(acc[1][ni][2] * inv, acc[1][ni][3] * inv);
            *(unsigned*)(bp + 16 + lg * 4)     = w2;
            *(unsigned*)(bp + 16 + lg * 4 + 2) = w3;
        } else {
            *(unsigned*)(bp + 28) = w2;
        }
    }
}

// ---------------------------------------------------------------------------
extern "C" void kernel_launch(void* const* d_in, const int* in_sizes, int n_in,
                              void* d_out, int out_size, void* d_ws, size_t ws_size,
                              hipStream_t stream)
{
    (void)in_sizes; (void)n_in; (void)out_size; (void)ws_size;
    const float* x      = (const float*)d_in[0];
    const int*   rpi    = (const int*)d_in[1];
    const float* n1w    = (const float*)d_in[2];
    const float* n1b    = (const float*)d_in[3];
    const float* qkv_w  = (const float*)d_in[4];
    const float* qkv_b  = (const float*)d_in[5];
    const float* rpb    = (const float*)d_in[6];
    const float* proj_w = (const float*)d_in[7];
    const float* proj_b = (const float*)d_in[8];
    const float* n2w    = (const float*)d_in[9];
    const float* n2b    = (const float*)d_in[10];
    const float* fc1_w  = (const float*)d_in[11];
    const float* fc1_b  = (const float*)d_in[12];
    const float* fc2_w  = (const float*)d_in[13];
    const float* fc2_b  = (const float*)d_in[14];
    float* out = (float*)d_out;

    char* ws = (char*)d_ws;
    size_t off = 0;
    auto alloc = [&](size_t bytes) -> void* {
        void* p = ws + off; off += (bytes + 511) & ~(size_t)511; return p;
    };
    u16*   xn     = (u16*)alloc(65536ull * 192 * 2);        // ln out; ao aliases
    u16*   q_g    = (u16*)alloc(65536ull * 192 * 2);        // [win][h][q][32]
    u16*   K_pad  = (u16*)alloc(6ull * 264 * 264 * 32 * 2); // [h][y][x][32]
    u16*   v_s    = (u16*)alloc(65536ull * 180 * 4);        // aliased with x2b
    u16*   x2b    = v_s;                                    // bf16 [t][192]
    u16*   vP     = (u16*)alloc(6ull * 32 * 264 * 272 * 2); // [h][d][y+4][x+4]
    u16*   bias5  = (u16*)alloc(6ull * 36 * 4 * 4 * 16 * 16 * 2);
    u16*   qkvT   = (u16*)alloc(640ull * 192 * 2);
    u16*   projT  = (u16*)alloc(256ull * 192 * 2);
    u16*   fc1T   = (u16*)alloc(384ull * 192 * 2);
    u16*   fc2T   = (u16*)alloc(256ull * 384 * 2);
    u16*   ao     = xn;    // ln1 zero-fills cols 180..191; attn fills 0..179
    u16*   h1     = q_g;   // fc1 out [t][384]: q_g+K_pad adjacent >= 50.3MB

    prepln_k<<<dim3(28168), dim3(256), 0, stream>>>(x, n1w, n1b, xn,
        qkv_w, proj_w, fc1_w, fc2_w, rpi, rpb,
        qkvT, projT, fc1T, fc2T, bias5, (unsigned*)K_pad, (unsigned*)vP);
    gemm_k<192, 3, 0><<<dim3(512, 3), dim3(256), 0, stream>>>(
        xn, qkvT, qkv_b, (const float*)nullptr, q_g, K_pad, v_s);
    vtr_k<<<dim3(256, 6), dim3(256), 0, stream>>>(v_s, vP);
    attn_k<<<dim3(256, 6), dim3(256), 0, stream>>>(q_g, K_pad, vP, bias5, ao);
    gemm_k<192, 3, 1><<<dim3(512, 1), dim3(256), 0, stream>>>(
        ao, projT, proj_b, x, x2b, nullptr, nullptr);
    lnb_k<<<dim3(16384), dim3(256), 0, stream>>>(x2b, n2w, n2b, xn);
    gemm_k<192, 3, 2><<<dim3(512, 2), dim3(256), 0, stream>>>(
        xn, fc1T, fc1_b, (const float*)nullptr, h1, nullptr, nullptr);
    gemm_k<384, 3, 3><<<dim3(512, 1), dim3(256), 0, stream>>>(
        h1, fc2T, fc2_b, (const float*)nullptr, out, x2b, nullptr);
}

// Round 13
// 248.037 us; speedup vs baseline: 1.2852x; 1.0821x over previous
//
#include <hip/hip_runtime.h>

typedef float f32x4 __attribute__((ext_vector_type(4)));
typedef float fvec4 __attribute__((ext_vector_type(4)));
typedef __bf16 bf16x8 __attribute__((ext_vector_type(8)));
typedef unsigned short u16;
typedef u16 u16x8 __attribute__((ext_vector_type(8)));
typedef u16 u16x4 __attribute__((ext_vector_type(4)));
typedef int i32x2 __attribute__((ext_vector_type(2)));

#define SCALE_Q 0.18257418583505536f   /* 30^-0.5 */
#define LOG2E   1.4426950408889634f
#define SCALE_Q2 (SCALE_Q * LOG2E)     /* folded: exp(s) = 2^(s*log2e) */

__device__ __forceinline__ u16 f2bf(float f) {
    union { __bf16 h; u16 u; } cv; cv.h = (__bf16)f; return cv.u;
}
__device__ __forceinline__ float bf2f(u16 u) {
    union { __bf16 h; u16 u; } cv; cv.u = u; return (float)cv.h;
}
__device__ __forceinline__ float exp2_raw(float x) {
    float r;
    asm("v_exp_f32 %0, %1" : "=v"(r) : "v"(x));
    return r;
}
__device__ __forceinline__ unsigned pk_bf16(float a, float b) {
    unsigned r;
    asm("v_cvt_pk_bf16_f32 %0, %1, %2" : "=v"(r) : "v"(a), "v"(b));
    return r;
}

// async global->LDS, 16B per lane; LDS dest = wave-uniform base + lane*16
#define GLD16(gsrc, ldst) __builtin_amdgcn_global_load_lds( \
    (const __attribute__((address_space(1))) unsigned*)(gsrc), \
    (__attribute__((address_space(3))) unsigned*)(ldst), 16, 0, 0)

// lane^16 cross-exchange pair
__device__ __forceinline__ void xswap16(int a, int b, int& u, int& v) {
#if __has_builtin(__builtin_amdgcn_permlane16_swap)
    i32x2 r = __builtin_amdgcn_permlane16_swap(a, b, false, false);
    u = r[0]; v = r[1];
#else
    int sa = __builtin_amdgcn_ds_swizzle(a, 0x401F);
    int sb = __builtin_amdgcn_ds_swizzle(b, 0x401F);
    bool hi = (threadIdx.x & 16) != 0;
    u = hi ? sb : a;
    v = hi ? b : sa;
#endif
}

// ---------------------------------------------------------------------------
// prep + ln1 merged. Weights now stored FRAGMENT-MAJOR: BtF[ng][k][lane][8]
// (ng = 16-col group, k = 32-dim K-step, lane = lg*16+l15) -> each MFMA
// B-fragment is one contiguous 1KB block, loaded as base + lane*16B
// (coalesced; a col-block's fragments fit L1).
// ---------------------------------------------------------------------------
__device__ __forceinline__ void border_yx(int i, int& y, int& x) {
    if (i < 1056)      { y = i / 264; x = i % 264; }
    else if (i < 2112) { int j = i - 1056; y = 260 + j / 264; x = j % 264; }
    else               { int j = i - 2112; y = 4 + (j >> 3); int xx = j & 7;
                         x = (xx < 4) ? xx : 256 + xx; }
}

__global__ __launch_bounds__(256)
void prepln_k(const float* __restrict__ x, const float* __restrict__ n1w,
              const float* __restrict__ n1b, u16* __restrict__ xn,
              const float* __restrict__ qkv_w, const float* __restrict__ proj_w,
              const float* __restrict__ fc1_w, const float* __restrict__ fc2_w,
              const int* __restrict__ rpi, const float* __restrict__ rpb,
              u16* __restrict__ qkvT, u16* __restrict__ projT,
              u16* __restrict__ fc1T, u16* __restrict__ fc2T,
              u16* __restrict__ bias5, unsigned* __restrict__ kp_u32,
              unsigned* __restrict__ vp_u32)
{
    if (blockIdx.x < 16384) {      // ----- LayerNorm1 -----
        int row = blockIdx.x * 4 + (threadIdx.x >> 6);
        int lane = threadIdx.x & 63;
        fvec4 v = {0.f, 0.f, 0.f, 0.f};
        if (lane < 45) v = *(const fvec4*)(x + (long)row * 180 + lane * 4);
        float s  = v.x + v.y + v.z + v.w;
        float sq = v.x * v.x + v.y * v.y + v.z * v.z + v.w * v.w;
        for (int m = 1; m < 64; m <<= 1) { s += __shfl_xor(s, m); sq += __shfl_xor(sq, m); }
        float mean = s * (1.f / 180.f);
        float var  = sq * (1.f / 180.f) - mean * mean;
        float rstd = rsqrtf(var + 1e-5f);
        if (lane < 45) {
            u16x4 o;
            #pragma unroll
            for (int j = 0; j < 4; j++) {
                int c = lane * 4 + j;
                o[j] = f2bf((v[j] - mean) * rstd * n1w[c] + n1b[c]);
            }
            *(u16x4*)(xn + (long)row * 192 + lane * 4) = o;
        } else if (lane < 48) {
            u16x4 z = {0, 0, 0, 0};
            *(u16x4*)(xn + (long)row * 192 + 180 + (lane - 45) * 4) = z;
        }
        return;
    }
    int idx = (blockIdx.x - 16384) * 256 + threadIdx.x;
    if (idx < 122880) {                        // qkvT frag-major: 40 ng x 6 k
        int e = idx & 7, l15b = (idx >> 3) & 15, lgb = (idx >> 7) & 3;
        int kstep = (idx >> 9) % 6, ng = idx / 3072;
        int col = ng * 16 + l15b, kd = kstep * 32 + lgb * 8 + e;
        qkvT[idx] = (col < 540 && kd < 180) ? f2bf(qkv_w[kd * 540 + col]) : (u16)0;
    } else if (idx < 172032) {                 // projT frag-major: 12 ng x 6 k
        int i = idx - 122880;
        int e = i & 7, l15b = (i >> 3) & 15, lgb = (i >> 7) & 3;
        int kstep = (i >> 9) % 6, ng = i / 3072;
        int col = ng * 16 + l15b, kd = kstep * 32 + lgb * 8 + e;
        projT[i] = (col < 180 && kd < 180) ? f2bf(proj_w[kd * 180 + col]) : (u16)0;
    } else if (idx < 245760) {                 // fc1T frag-major: 24 ng x 6 k
        int i = idx - 172032;
        int e = i & 7, l15b = (i >> 3) & 15, lgb = (i >> 7) & 3;
        int kstep = (i >> 9) % 6, ng = i / 3072;
        int col = ng * 16 + l15b, kd = kstep * 32 + lgb * 8 + e;
        fc1T[i] = (col < 360 && kd < 180) ? f2bf(fc1_w[kd * 360 + col]) : (u16)0;
    } else if (idx < 344064) {                 // fc2T frag-major: 12 ng x 12 k
        int i = idx - 245760;
        int e = i & 7, l15b = (i >> 3) & 15, lgb = (i >> 7) & 3;
        int kstep = (i >> 9) % 12, ng = i / 6144;
        int col = ng * 16 + l15b, kd = kstep * 32 + lgb * 8 + e;
        fc2T[i] = (col < 180 && kd < 360) ? f2bf(fc2_w[kd * 180 + col]) : (u16)0;
    } else if (idx < 1228800) {                // bias5[(h*36+ch*4+mi)][lg][wv][l15][e]
        int i = idx - 344064;
        int e = i & 15, l15 = (i >> 4) & 15, wv2 = (i >> 8) & 3, lg2 = (i >> 10) & 3;
        int cm36 = i >> 12;
        int hh = cm36 / 36, cm = cm36 % 36;
        int ch = cm >> 2, mi = cm & 3;
        int ni = e >> 2, rr = e & 3;
        int q = wv2 * 64 + ni * 16 + l15;
        int key = ch * 64 + mi * 16 + lg2 * 4 + rr;
        bias5[i] = f2bf(rpb[rpi[q * 576 + key] * 6 + hh] * LOG2E);
    } else if (idx < 1628160) {                // K_pad border tokens (u32 x16)
        int i = idx - 1228800;
        int tok = i >> 4, wj = i & 15;
        int h = tok / 4160, b = tok % 4160, y, xx;
        border_yx(b, y, xx);
        kp_u32[((h * 264 + y) * 264 + xx) * 16 + wj] = 0u;
    } else if (idx < 2021376) {                // K_pad interior dims 30,31
        int i = idx - 1628160;
        int h = i / 65536, t = i % 65536;
        int y = t >> 8, xx = t & 255;
        kp_u32[((h * 264 + y + 4) * 264 + xx + 4) * 16 + 15] = 0u;
    } else if (idx < 2236800) {                // vP d=30 plane := 1.0
        int i = idx - 2021376;
        int h = i / 35904, r = i % 35904;
        vp_u32[(h * 32 + 30) * 35904 + r] = 0x3F803F80u;
    } else if (idx < 2452224) {                // vP d=31 plane := 0
        int i = idx - 2236800;
        int h = i / 35904, r = i % 35904;
        vp_u32[(h * 32 + 31) * 35904 + r] = 0u;
    } else if (idx < 3016704) {                // vP d<30 borders := 0
        int i = idx - 2452224;
        int hd = i / 3136, j = i % 3136;
        int h = hd / 30, d = hd % 30;
        int y, xu;
        if (j < 1088) { int r = j / 136; y = r + (r >= 4 ? 256 : 0); xu = j % 136; }
        else { int j2 = j - 1088; y = 4 + (j2 >> 3); int q = j2 & 7;
               xu = (q < 2) ? q : 128 + q; }
        vp_u32[((h * 32 + d) * 264 + y) * 136 + xu] = 0u;
    }
}

// ---------------------------------------------------------------------------
// LayerNorm over bf16 input (x2 residual stream) -> bf16 [row][192]
// ---------------------------------------------------------------------------
__global__ __launch_bounds__(256)
void lnb_k(const u16* __restrict__ in, const float* __restrict__ w,
           const float* __restrict__ b, u16* __restrict__ out)
{
    int row = blockIdx.x * 4 + (threadIdx.x >> 6);
    int lane = threadIdx.x & 63;
    fvec4 v = {0.f, 0.f, 0.f, 0.f};
    if (lane < 45) {
        u16x4 raw = *(const u16x4*)(in + (long)row * 192 + lane * 4);
        #pragma unroll
        for (int j = 0; j < 4; j++) v[j] = bf2f(raw[j]);
    }
    float s  = v.x + v.y + v.z + v.w;
    float sq = v.x * v.x + v.y * v.y + v.z * v.z + v.w * v.w;
    for (int m = 1; m < 64; m <<= 1) { s += __shfl_xor(s, m); sq += __shfl_xor(sq, m); }
    float mean = s * (1.f / 180.f);
    float var  = sq * (1.f / 180.f) - mean * mean;
    float rstd = rsqrtf(var + 1e-5f);
    if (lane < 45) {
        u16x4 o;
        #pragma unroll
        for (int j = 0; j < 4; j++) {
            int c = lane * 4 + j;
            o[j] = f2bf((v[j] - mean) * rstd * w[c] + b[c]);
        }
        *(u16x4*)(out + (long)row * 192 + lane * 4) = o;
    } else if (lane < 48) {
        u16x4 z = {0, 0, 0, 0};
        *(u16x4*)(out + (long)row * 192 + 180 + (lane - 45) * 4) = z;
    }
}

// ---------------------------------------------------------------------------
// A-resident GEMM (r10/r12 shape): 128-row panel, 48KB LDS, 4 waves 2x2,
// wave tile 64x32 (acc[4][2]), blockIdx.y z-split of col-groups. B fragments
// loaded COALESCED from fragment-major BtF (1KB contiguous per fragment,
// L1-resident across row-blocks). qkv epilogue writes V directly into planar
// vP (vtr kernel eliminated).
// ---------------------------------------------------------------------------
template<int KTOT, int NCB, int EPI>
__global__ __launch_bounds__(256)
void gemm_k(const u16* __restrict__ A, const u16* __restrict__ BtF,
            const float* __restrict__ bias, const float* __restrict__ resid,
            void* __restrict__ o0, void* __restrict__ o1, void* __restrict__ o2)
{
    constexpr int NH = KTOT / 192;             // K-halves (1 or 2)
    constexpr int NKT = KTOT / 32;             // total K-steps
    constexpr int AC = (NH == 1) ? 1 : NCB;
    __shared__ u16 lds_a[128 * 192];           // 48 KB
    const int tid = threadIdx.x;
    const int l = tid & 63, wv = tid >> 6;
    const int wm = wv >> 1, wn = wv & 1;
    const int l15 = l & 15, lg = l >> 4;
    const int rx7 = l15 & 7;
    const long rowb = (long)blockIdx.x * 128;
    const int cb0 = blockIdx.y * NCB;
    const f32x4 fz = {0.f, 0.f, 0.f, 0.f};

    f32x4 acc[AC][4][2];
    #pragma unroll
    for (int a2 = 0; a2 < AC; a2++)
        #pragma unroll
        for (int i = 0; i < 4; i++) { acc[a2][i][0] = fz; acc[a2][i][1] = fz; }

    const u16* aptr[4];
    #pragma unroll
    for (int mi = 0; mi < 4; mi++)
        aptr[mi] = lds_a + (wm * 64 + mi * 16 + l15) * 192;

    auto epilogue = [&](int cb, f32x4 (&ac)[4][2]) {
        #pragma unroll
        for (int nd = 0; nd < 2; nd++) {
            const int c = cb * 64 + wn * 32 + nd * 16 + l15;
            if (EPI == 0) {
                if (c < 540) {
                    const float bb = bias[c];
                    const int sec = (c >= 360) ? 2 : ((c >= 180) ? 1 : 0);
                    const int cc = c - sec * 180;
                    const int hh = cc / 30, d = cc - hh * 30;
                    #pragma unroll
                    for (int mi = 0; mi < 4; mi++) {
                        const long t0 = rowb + wm * 64 + mi * 16 + lg * 4;
                        const int y = (int)(t0 >> 8), x0 = (int)(t0 & 255);
                        if (sec == 0) {
                            int win = ((y >> 4) << 4) | (x0 >> 4);
                            int qrow0 = ((y & 15) << 4) | (x0 & 15);
                            u16* dst = (u16*)o0 + (((long)(win * 6 + hh)) * 256 + qrow0) * 32 + d;
                            #pragma unroll
                            for (int rr = 0; rr < 4; rr++)
                                dst[rr * 32] = f2bf((ac[mi][nd][rr] + bb) * SCALE_Q2);
                        } else if (sec == 1) {
                            u16* dst = (u16*)o1 + (((long)hh * 264 + y + 4) * 264 + x0 + 4) * 32 + d;
                            #pragma unroll
                            for (int rr = 0; rr < 4; rr++)
                                dst[rr * 32] = f2bf(ac[mi][nd][rr] + bb);
                        } else {
                            // V directly into planar vP[h][d][y+4][x+4]
                            long dstoff = (((long)hh * 32 + d) * 264 + y + 4) * 272 + x0 + 4;
                            union { u16x4 v4; unsigned u2[2]; } pv;
                            pv.u2[0] = pk_bf16(ac[mi][nd][0] + bb, ac[mi][nd][1] + bb);
                            pv.u2[1] = pk_bf16(ac[mi][nd][2] + bb, ac[mi][nd][3] + bb);
                            *(u16x4*)((u16*)o2 + dstoff) = pv.v4;
                        }
                    }
                }
            } else if (EPI == 1) {
                if (c < 180) {
                    const float bb = bias[c];
                    #pragma unroll
                    for (int mi = 0; mi < 4; mi++) {
                        const long t0 = rowb + wm * 64 + mi * 16 + lg * 4;
                        const float* rs = resid + t0 * 180 + c;
                        u16* dst = (u16*)o0 + t0 * 192 + c;
                        #pragma unroll
                        for (int rr = 0; rr < 4; rr++)
                            dst[rr * 192] = f2bf(ac[mi][nd][rr] + bb + rs[rr * 180]);
                    }
                }
            } else if (EPI == 2) {
                const float bb = (c < 360) ? bias[c] : 0.f;
                #pragma unroll
                for (int mi = 0; mi < 4; mi++) {
                    const long t0 = rowb + wm * 64 + mi * 16 + lg * 4;
                    u16* dst = (u16*)o0 + t0 * 384 + c;
                    #pragma unroll
                    for (int rr = 0; rr < 4; rr++) {
                        float xx = ac[mi][nd][rr] + bb;
                        float u2n = -2.f * xx * (0.7978845608f + 0.0356774081f * xx * xx);
                        dst[rr * 384] = f2bf(xx / (1.f + __expf(u2n)));
                    }
                }
            } else {
                if (c < 180) {
                    const float bb = bias[c];
                    const u16* x2b = (const u16*)o1;
                    #pragma unroll
                    for (int mi = 0; mi < 4; mi++) {
                        const long t0 = rowb + wm * 64 + mi * 16 + lg * 4;
                        const u16* rs = x2b + t0 * 192 + c;
                        float* dst = (float*)o0 + t0 * 180 + c;
                        #pragma unroll
                        for (int rr = 0; rr < 4; rr++)
                            dst[rr * 180] = ac[mi][nd][rr] + bb + bf2f(rs[rr * 192]);
                    }
                }
            }
        }
    };

    #pragma unroll
    for (int hk = 0; hk < NH; ++hk) {
        if (hk) __syncthreads();               // all waves done with prev half
        #pragma unroll
        for (int R = 0; R < 12; ++R) {         // stage A: 128 rows x 24 granules
            int idx = R * 256 + tid;
            int row = idx / 24, gp = idx - row * 24;
            int g = (gp & 24) | ((gp & 7) ^ (row & 7));
            GLD16(A + (rowb + row) * KTOT + hk * 192 + g * 8,
                  (char*)lds_a + R * 4096 + wv * 1024);
        }
        __syncthreads();                       // A half ready (drains vmcnt)

        #pragma unroll
        for (int icb = 0; icb < NCB; ++icb) {
            f32x4 (&ac)[4][2] = acc[(NH == 1) ? 0 : icb];
            // fragment-major B: frag fi = ng*NKT + kidx, 512 u16 each,
            // lane offset l*8 -> coalesced 16B/lane
            const u16* Bf = BtF + ((long)((cb0 + icb) * 4 + wn * 2) * NKT + hk * 6) * 512 + l * 8;
            #pragma unroll
            for (int kg = 0; kg < 6; kg += 3) {
                bf16x8 bfr[2][3];
                #pragma unroll
                for (int g2 = 0; g2 < 3; ++g2) {
                    bfr[0][g2] = *(const bf16x8*)(Bf + (kg + g2) * 512);
                    bfr[1][g2] = *(const bf16x8*)(Bf + (NKT + kg + g2) * 512);
                }
                #pragma unroll
                for (int g2 = 0; g2 < 3; ++g2) {
                    const int k = kg + g2;
                    const int gk = k * 4 + lg;
                    const int gpk = (gk & 24) | ((gk & 7) ^ rx7);
                    bf16x8 af[4];
                    #pragma unroll
                    for (int mi = 0; mi < 4; mi++)
                        af[mi] = *(const bf16x8*)(aptr[mi] + gpk * 8);
                    #pragma unroll
                    for (int mi = 0; mi < 4; mi++)
                        #pragma unroll
                        for (int nd = 0; nd < 2; nd++)
                            ac[mi][nd] = __builtin_amdgcn_mfma_f32_16x16x32_bf16(af[mi], bfr[nd][g2], ac[mi][nd], 0, 0, 0);
                }
            }
            if (NH == 1) {
                epilogue(cb0 + icb, ac);
                #pragma unroll
                for (int i = 0; i < 4; i++) { ac[i][0] = fz; ac[i][1] = fz; }
            }
        }
    }
    if (NH == 2) {
        #pragma unroll
        for (int icb = 0; icb < NCB; ++icb) epilogue(cb0 + icb, acc[icb]);
    }
}

// ---------------------------------------------------------------------------
// Attention (r12, unchanged): block=(window,head), 4 waves x 64 q, 9 chunks.
// ---------------------------------------------------------------------------
__global__ __launch_bounds__(256)
void attn_k(const u16* __restrict__ q_g, const u16* __restrict__ K_pad,
            const u16* __restrict__ vP, const u16* __restrict__ bias5,
            u16* __restrict__ attn_out)
{
    __shared__ u16 kc[2][64 * 32];
    __shared__ u16 vt[2][32 * 64];

    const int w = ((blockIdx.x & 7) << 5) | (blockIdx.x >> 3);   // XCD swizzle
    const int h = blockIdx.y;
    const int wy = w >> 4, wx = w & 15;
    const int tid = threadIdx.x;
    const int wv = tid >> 6, l = tid & 63;
    const int l15 = l & 15, lg = l >> 4;
    const int swzk = (l15 >> 1) & 3;
    const int swzv = l15 & 7;

    bf16x8 qb[4];
    #pragma unroll
    for (int ni = 0; ni < 4; ni++) {
        int qrow = wv * 64 + ni * 16 + l15;
        qb[ni] = *(const bf16x8*)(q_g + (((long)(w * 6 + h)) * 256 + qrow) * 32 + lg * 8);
    }

    f32x4 acc[2][4];
    #pragma unroll
    for (int i = 0; i < 2; i++)
        #pragma unroll
        for (int j = 0; j < 4; j++) acc[i][j] = (f32x4){0.f, 0.f, 0.f, 0.f};

    const int tK = tid >> 2;
    const int gtk = (l & 3) ^ ((l >> 3) & 3);
    const int aK = (tK >= 48) ? 2 : (tK >= 24 ? 1 : 0);
    const int bK = tK - aK * 24;
    const u16* KbaseRow = K_pad + (((long)(h * 264 + wy * 16)) * 264 + wx * 16) * 32 + gtk * 8;
    const int dV = tid >> 3;
    const int gtv = (l & 7) ^ (l >> 3);
    const int aV = gtv / 3, bV = (gtv % 3) * 8;
    const u16* Vrow0 = vP + ((((long)h * 32 + dV) * 264) + wy * 16) * 272 + wx * 16;
    const u16* Bp = bias5 + (long)h * 147456 + ((lg * 4 + wv) * 16 + l15) * 16;

    GLD16(KbaseRow + ((long)aK * 264 + bK) * 32, (char*)kc[0] + wv * 1024);
    GLD16(Vrow0 + aV * 272 + bV, (char*)vt[0] + wv * 1024);

    u16x8 bl[4], bh[4];
    #pragma unroll
    for (int mi = 0; mi < 4; mi++) {
        bl[mi] = *(const u16x8*)(Bp + mi * 4096);
        bh[mi] = *(const u16x8*)(Bp + mi * 4096 + 8);
    }

    #pragma unroll
    for (int ch = 0; ch < 9; ++ch) {
        __syncthreads();
        u16x8 bln[4], bhn[4];
        if (ch < 8) {   // prefetch chunk ch+1: K, V, bias
            int n = (ch + 1) * 64;
            int c1 = n / 24, c2 = n - c1 * 24;
            int bb2 = bK + c2;
            int t2 = bb2 >= 24;
            int oy = c1 + aK + t2, ox = bb2 - (t2 ? 24 : 0);
            GLD16(KbaseRow + ((long)oy * 264 + ox) * 32, (char*)kc[(ch + 1) & 1] + wv * 1024);
            int bbv = bV + c2;
            int t2v = bbv >= 24;
            int oyv = c1 + aV + t2v, oxv = bbv - (t2v ? 24 : 0);
            GLD16(Vrow0 + oyv * 272 + oxv, (char*)vt[(ch + 1) & 1] + wv * 1024);
            #pragma unroll
            for (int mi = 0; mi < 4; mi++) {
                bln[mi] = *(const u16x8*)(Bp + ((ch + 1) * 4 + mi) * 4096);
                bhn[mi] = *(const u16x8*)(Bp + ((ch + 1) * 4 + mi) * 4096 + 8);
            }
        }
        const u16* kcur = kc[ch & 1];
        const u16* vcur = vt[ch & 1];

        #pragma unroll
        for (int ks = 0; ks < 2; ++ks) {
            int Wp[2][4][2];
            #pragma unroll
            for (int mih = 0; mih < 2; ++mih) {
                int mi = ks * 2 + mih;
                int key = ks * 32 + mih * 16 + l15;
                bf16x8 ka = *(const bf16x8*)(kcur + key * 32 + (lg ^ swzk) * 8);
                union { u16x8 v; unsigned d[4]; } ulo, uhi;
                ulo.v = bl[mi]; uhi.v = bh[mi];
                f32x4 s[4];
                #pragma unroll
                for (int ni = 0; ni < 4; ni++) {
                    unsigned dA = (ni < 2) ? ulo.d[(ni & 1) * 2]     : uhi.d[(ni & 1) * 2];
                    unsigned dB = (ni < 2) ? ulo.d[(ni & 1) * 2 + 1] : uhi.d[(ni & 1) * 2 + 1];
                    f32x4 ci;
                    ci[0] = __uint_as_float(dA << 16);
                    ci[1] = __uint_as_float(dA & 0xFFFF0000u);
                    ci[2] = __uint_as_float(dB << 16);
                    ci[3] = __uint_as_float(dB & 0xFFFF0000u);
                    s[ni] = ci;
                }
                #pragma unroll
                for (int ni = 0; ni < 4; ni++)
                    s[ni] = __builtin_amdgcn_mfma_f32_16x16x32_bf16(ka, qb[ni], s[ni], 0, 0, 0);
                #pragma unroll
                for (int ni = 0; ni < 4; ni++) {
                    float p0 = exp2_raw(s[ni][0]);
                    float p1 = exp2_raw(s[ni][1]);
                    float p2 = exp2_raw(s[ni][2]);
                    float p3 = exp2_raw(s[ni][3]);
                    Wp[mih][ni][0] = (int)pk_bf16(p0, p1);
                    Wp[mih][ni][1] = (int)pk_bf16(p2, p3);
                }
            }
            bf16x8 va0 = *(const bf16x8*)(vcur + l15 * 64 + ((ks * 4 + lg) ^ swzv) * 8);
            bf16x8 va1 = *(const bf16x8*)(vcur + (16 + l15) * 64 + ((ks * 4 + lg) ^ swzv) * 8);
            #pragma unroll
            for (int ni = 0; ni < 4; ni++) {
                i32x2 r0 = __builtin_amdgcn_permlane32_swap(Wp[0][ni][0], Wp[1][ni][0], false, false);
                i32x2 r1 = __builtin_amdgcn_permlane32_swap(Wp[0][ni][1], Wp[1][ni][1], false, false);
                int wd0, wd1, wd2, wd3;
                xswap16(r0[0], r0[1], wd0, wd2);
                xswap16(r1[0], r1[1], wd1, wd3);
                union { int wd[4]; bf16x8 v; } pu;
                pu.wd[0] = wd0; pu.wd[1] = wd1; pu.wd[2] = wd2; pu.wd[3] = wd3;
                acc[0][ni] = __builtin_amdgcn_mfma_f32_16x16x32_bf16(va0, pu.v, acc[0][ni], 0, 0, 0);
                acc[1][ni] = __builtin_amdgcn_mfma_f32_16x16x32_bf16(va1, pu.v, acc[1][ni], 0, 0, 0);
            }
        }
        if (ch < 8) {
            #pragma unroll
            for (int mi = 0; mi < 4; mi++) { bl[mi] = bln[mi]; bh[mi] = bhn[mi]; }
        }
    }

    #pragma unroll
    for (int ni = 0; ni < 4; ni++) {
        float sum = __shfl(acc[1][ni][2], 48 + l15);
        float inv = 1.f / sum;
        int q = wv * 64 + ni * 16 + l15;
        int y = wy * 16 + (q >> 4), x = wx * 16 + (q & 15);
        u16* bp = attn_out + ((long)(y * 256 + x)) * 192 + h * 30;
        unsigned w0 = pk_bf16(acc[0][ni][0] * inv, acc[0][ni][1] * inv);
        unsigned w1 = pk_bf16(acc[0][ni][2] * inv, acc[0][ni][3] * inv);
        *(unsigned*)(bp + lg * 4)     = w0;
        *(unsigned*)(bp + lg * 4 + 2) = w1;
        unsigned w2 = pk_bf16(acc[1][ni][0] * inv, acc[1][ni][1] * inv);
        if (lg < 3) {
            unsigned w3 = pk_bf16(acc[1][ni][2] * inv, acc[1][ni][3] * inv);
            *(unsigned*)(bp + 16 + lg * 4)     = w2;
            *(unsigned*)(bp + 16 + lg * 4 + 2) = w3;
        } else {
            *(unsigned*)(bp + 28) = w2;
        }
    }
}

// ---------------------------------------------------------------------------
extern "C" void kernel_launch(void* const* d_in, const int* in_sizes, int n_in,
                              void* d_out, int out_size, void* d_ws, size_t ws_size,
                              hipStream_t stream)
{
    (void)in_sizes; (void)n_in; (void)out_size; (void)ws_size;
    const float* x      = (const float*)d_in[0];
    const int*   rpi    = (const int*)d_in[1];
    const float* n1w    = (const float*)d_in[2];
    const float* n1b    = (const float*)d_in[3];
    const float* qkv_w  = (const float*)d_in[4];
    const float* qkv_b  = (const float*)d_in[5];
    const float* rpb    = (const float*)d_in[6];
    const float* proj_w = (const float*)d_in[7];
    const float* proj_b = (const float*)d_in[8];
    const float* n2w    = (const float*)d_in[9];
    const float* n2b    = (const float*)d_in[10];
    const float* fc1_w  = (const float*)d_in[11];
    const float* fc1_b  = (const float*)d_in[12];
    const float* fc2_w  = (const float*)d_in[13];
    const float* fc2_b  = (const float*)d_in[14];
    float* out = (float*)d_out;

    char* ws = (char*)d_ws;
    size_t off = 0;
    auto alloc = [&](size_t bytes) -> void* {
        void* p = ws + off; off += (bytes + 511) & ~(size_t)511; return p;
    };
    u16*   xn     = (u16*)alloc(65536ull * 192 * 2);        // ln out; ao aliases
    u16*   q_g    = (u16*)alloc(65536ull * 192 * 2);        // [win][h][q][32]
    u16*   K_pad  = (u16*)alloc(6ull * 264 * 264 * 32 * 2); // [h][y][x][32]
    u16*   x2b    = (u16*)alloc(65536ull * 192 * 2);        // bf16 resid stream
    u16*   vP     = (u16*)alloc(6ull * 32 * 264 * 272 * 2); // [h][d][y+4][x+4]
    u16*   bias5  = (u16*)alloc(6ull * 36 * 4 * 4 * 16 * 16 * 2);
    u16*   qkvT   = (u16*)alloc(640ull * 192 * 2);
    u16*   projT  = (u16*)alloc(256ull * 192 * 2);
    u16*   fc1T   = (u16*)alloc(384ull * 192 * 2);
    u16*   fc2T   = (u16*)alloc(256ull * 384 * 2);
    u16*   ao     = xn;    // ln1 zero-fills cols 180..191; attn fills 0..179
    u16*   h1     = q_g;   // fc1 out [t][384]: q_g+K_pad adjacent >= 50.3MB

    prepln_k<<<dim3(28168), dim3(256), 0, stream>>>(x, n1w, n1b, xn,
        qkv_w, proj_w, fc1_w, fc2_w, rpi, rpb,
        qkvT, projT, fc1T, fc2T, bias5, (unsigned*)K_pad, (unsigned*)vP);
    gemm_k<192, 3, 0><<<dim3(512, 3), dim3(256), 0, stream>>>(
        xn, qkvT, qkv_b, (const float*)nullptr, q_g, K_pad, vP);
    attn_k<<<dim3(256, 6), dim3(256), 0, stream>>>(q_g, K_pad, vP, bias5, ao);
    gemm_k<192, 3, 1><<<dim3(512, 1), dim3(256), 0, stream>>>(
        ao, projT, proj_b, x, x2b, nullptr, nullptr);
    lnb_k<<<dim3(16384), dim3(256), 0, stream>>>(x2b, n2w, n2b, xn);
    gemm_k<192, 3, 2><<<dim3(512, 2), dim3(256), 0, stream>>>(
        xn, fc1T, fc1_b, (const float*)nullptr, h1, nullptr, nullptr);
    gemm_k<384, 3, 3><<<dim3(512, 1), dim3(256), 0, stream>>>(
        h1, fc2T, fc2_b, (const float*)nullptr, out, x2b, nullptr);
}

// Round 14
// 218.691 us; speedup vs baseline: 1.4576x; 1.1342x over previous
//
#include <hip/hip_runtime.h>

typedef float f32x4 __attribute__((ext_vector_type(4)));
typedef float fvec4 __attribute__((ext_vector_type(4)));
typedef __bf16 bf16x8 __attribute__((ext_vector_type(8)));
typedef unsigned short u16;
typedef u16 u16x8 __attribute__((ext_vector_type(8)));
typedef u16 u16x4 __attribute__((ext_vector_type(4)));
typedef int i32x2 __attribute__((ext_vector_type(2)));

#define SCALE_Q 0.18257418583505536f   /* 30^-0.5 */
#define LOG2E   1.4426950408889634f
#define SCALE_Q2 (SCALE_Q * LOG2E)     /* folded: exp(s) = 2^(s*log2e) */

__device__ __forceinline__ u16 f2bf(float f) {
    union { __bf16 h; u16 u; } cv; cv.h = (__bf16)f; return cv.u;
}
__device__ __forceinline__ float bf2f(u16 u) {
    union { __bf16 h; u16 u; } cv; cv.u = u; return (float)cv.h;
}
__device__ __forceinline__ float exp2_raw(float x) {
    float r;
    asm("v_exp_f32 %0, %1" : "=v"(r) : "v"(x));
    return r;
}
__device__ __forceinline__ unsigned pk_bf16(float a, float b) {
    unsigned r;
    asm("v_cvt_pk_bf16_f32 %0, %1, %2" : "=v"(r) : "v"(a), "v"(b));
    return r;
}

// async global->LDS, 16B per lane; LDS dest = wave-uniform base + lane*16
#define GLD16(gsrc, ldst) __builtin_amdgcn_global_load_lds( \
    (const __attribute__((address_space(1))) unsigned*)(gsrc), \
    (__attribute__((address_space(3))) unsigned*)(ldst), 16, 0, 0)

// lane^16 cross-exchange pair
__device__ __forceinline__ void xswap16(int a, int b, int& u, int& v) {
#if __has_builtin(__builtin_amdgcn_permlane16_swap)
    i32x2 r = __builtin_amdgcn_permlane16_swap(a, b, false, false);
    u = r[0]; v = r[1];
#else
    int sa = __builtin_amdgcn_ds_swizzle(a, 0x401F);
    int sb = __builtin_amdgcn_ds_swizzle(b, 0x401F);
    bool hi = (threadIdx.x & 16) != 0;
    u = hi ? sb : a;
    v = hi ? b : sa;
#endif
}

// ---------------------------------------------------------------------------
// prep + ln1 merged. Weights fragment-major (r13): BtF[ng][k][lane][8].
// ---------------------------------------------------------------------------
__device__ __forceinline__ void border_yx(int i, int& y, int& x) {
    if (i < 1056)      { y = i / 264; x = i % 264; }
    else if (i < 2112) { int j = i - 1056; y = 260 + j / 264; x = j % 264; }
    else               { int j = i - 2112; y = 4 + (j >> 3); int xx = j & 7;
                         x = (xx < 4) ? xx : 256 + xx; }
}

__global__ __launch_bounds__(256)
void prepln_k(const float* __restrict__ x, const float* __restrict__ n1w,
              const float* __restrict__ n1b, u16* __restrict__ xn,
              const float* __restrict__ qkv_w, const float* __restrict__ proj_w,
              const float* __restrict__ fc1_w, const float* __restrict__ fc2_w,
              const int* __restrict__ rpi, const float* __restrict__ rpb,
              u16* __restrict__ qkvT, u16* __restrict__ projT,
              u16* __restrict__ fc1T, u16* __restrict__ fc2T,
              u16* __restrict__ bias5, unsigned* __restrict__ kp_u32,
              unsigned* __restrict__ vp_u32)
{
    if (blockIdx.x < 16384) {      // ----- LayerNorm1 -----
        int row = blockIdx.x * 4 + (threadIdx.x >> 6);
        int lane = threadIdx.x & 63;
        fvec4 v = {0.f, 0.f, 0.f, 0.f};
        if (lane < 45) v = *(const fvec4*)(x + (long)row * 180 + lane * 4);
        float s  = v.x + v.y + v.z + v.w;
        float sq = v.x * v.x + v.y * v.y + v.z * v.z + v.w * v.w;
        for (int m = 1; m < 64; m <<= 1) { s += __shfl_xor(s, m); sq += __shfl_xor(sq, m); }
        float mean = s * (1.f / 180.f);
        float var  = sq * (1.f / 180.f) - mean * mean;
        float rstd = rsqrtf(var + 1e-5f);
        if (lane < 45) {
            u16x4 o;
            #pragma unroll
            for (int j = 0; j < 4; j++) {
                int c = lane * 4 + j;
                o[j] = f2bf((v[j] - mean) * rstd * n1w[c] + n1b[c]);
            }
            *(u16x4*)(xn + (long)row * 192 + lane * 4) = o;
        } else if (lane < 48) {
            u16x4 z = {0, 0, 0, 0};
            *(u16x4*)(xn + (long)row * 192 + 180 + (lane - 45) * 4) = z;
        }
        return;
    }
    int idx = (blockIdx.x - 16384) * 256 + threadIdx.x;
    if (idx < 122880) {                        // qkvT frag-major: 40 ng x 6 k
        int e = idx & 7, l15b = (idx >> 3) & 15, lgb = (idx >> 7) & 3;
        int kstep = (idx >> 9) % 6, ng = idx / 3072;
        int col = ng * 16 + l15b, kd = kstep * 32 + lgb * 8 + e;
        qkvT[idx] = (col < 540 && kd < 180) ? f2bf(qkv_w[kd * 540 + col]) : (u16)0;
    } else if (idx < 172032) {                 // projT frag-major: 12 ng x 6 k
        int i = idx - 122880;
        int e = i & 7, l15b = (i >> 3) & 15, lgb = (i >> 7) & 3;
        int kstep = (i >> 9) % 6, ng = i / 3072;
        int col = ng * 16 + l15b, kd = kstep * 32 + lgb * 8 + e;
        projT[i] = (col < 180 && kd < 180) ? f2bf(proj_w[kd * 180 + col]) : (u16)0;
    } else if (idx < 245760) {                 // fc1T frag-major: 24 ng x 6 k
        int i = idx - 172032;
        int e = i & 7, l15b = (i >> 3) & 15, lgb = (i >> 7) & 3;
        int kstep = (i >> 9) % 6, ng = i / 3072;
        int col = ng * 16 + l15b, kd = kstep * 32 + lgb * 8 + e;
        fc1T[i] = (col < 360 && kd < 180) ? f2bf(fc1_w[kd * 360 + col]) : (u16)0;
    } else if (idx < 344064) {                 // fc2T frag-major: 12 ng x 12 k
        int i = idx - 245760;
        int e = i & 7, l15b = (i >> 3) & 15, lgb = (i >> 7) & 3;
        int kstep = (i >> 9) % 12, ng = i / 6144;
        int col = ng * 16 + l15b, kd = kstep * 32 + lgb * 8 + e;
        fc2T[i] = (col < 180 && kd < 360) ? f2bf(fc2_w[kd * 180 + col]) : (u16)0;
    } else if (idx < 1228800) {                // bias5[(h*36+ch*4+mi)][lg][wv][l15][e]
        int i = idx - 344064;
        int e = i & 15, l15 = (i >> 4) & 15, wv2 = (i >> 8) & 3, lg2 = (i >> 10) & 3;
        int cm36 = i >> 12;
        int hh = cm36 / 36, cm = cm36 % 36;
        int ch = cm >> 2, mi = cm & 3;
        int ni = e >> 2, rr = e & 3;
        int q = wv2 * 64 + ni * 16 + l15;
        int key = ch * 64 + mi * 16 + lg2 * 4 + rr;
        bias5[i] = f2bf(rpb[rpi[q * 576 + key] * 6 + hh] * LOG2E);
    } else if (idx < 1628160) {                // K_pad border tokens (u32 x16)
        int i = idx - 1228800;
        int tok = i >> 4, wj = i & 15;
        int h = tok / 4160, b = tok % 4160, y, xx;
        border_yx(b, y, xx);
        kp_u32[((h * 264 + y) * 264 + xx) * 16 + wj] = 0u;
    } else if (idx < 2021376) {                // K_pad interior dims 30,31
        int i = idx - 1628160;
        int h = i / 65536, t = i % 65536;
        int y = t >> 8, xx = t & 255;
        kp_u32[((h * 264 + y + 4) * 264 + xx + 4) * 16 + 15] = 0u;
    } else if (idx < 2236800) {                // vP d=30 plane := 1.0
        int i = idx - 2021376;
        int h = i / 35904, r = i % 35904;
        vp_u32[(h * 32 + 30) * 35904 + r] = 0x3F803F80u;
    } else if (idx < 2452224) {                // vP d=31 plane := 0
        int i = idx - 2236800;
        int h = i / 35904, r = i % 35904;
        vp_u32[(h * 32 + 31) * 35904 + r] = 0u;
    } else if (idx < 3016704) {                // vP d<30 borders := 0
        int i = idx - 2452224;
        int hd = i / 3136, j = i % 3136;
        int h = hd / 30, d = hd % 30;
        int y, xu;
        if (j < 1088) { int r = j / 136; y = r + (r >= 4 ? 256 : 0); xu = j % 136; }
        else { int j2 = j - 1088; y = 4 + (j2 >> 3); int q = j2 & 7;
               xu = (q < 2) ? q : 128 + q; }
        vp_u32[((h * 32 + d) * 264 + y) * 136 + xu] = 0u;
    }
}

// ---------------------------------------------------------------------------
// LayerNorm over bf16 input (x2 residual stream) -> bf16 [row][192]
// ---------------------------------------------------------------------------
__global__ __launch_bounds__(256)
void lnb_k(const u16* __restrict__ in, const float* __restrict__ w,
           const float* __restrict__ b, u16* __restrict__ out)
{
    int row = blockIdx.x * 4 + (threadIdx.x >> 6);
    int lane = threadIdx.x & 63;
    fvec4 v = {0.f, 0.f, 0.f, 0.f};
    if (lane < 45) {
        u16x4 raw = *(const u16x4*)(in + (long)row * 192 + lane * 4);
        #pragma unroll
        for (int j = 0; j < 4; j++) v[j] = bf2f(raw[j]);
    }
    float s  = v.x + v.y + v.z + v.w;
    float sq = v.x * v.x + v.y * v.y + v.z * v.z + v.w * v.w;
    for (int m = 1; m < 64; m <<= 1) { s += __shfl_xor(s, m); sq += __shfl_xor(sq, m); }
    float mean = s * (1.f / 180.f);
    float var  = sq * (1.f / 180.f) - mean * mean;
    float rstd = rsqrtf(var + 1e-5f);
    if (lane < 45) {
        u16x4 o;
        #pragma unroll
        for (int j = 0; j < 4; j++) {
            int c = lane * 4 + j;
            o[j] = f2bf((v[j] - mean) * rstd * w[c] + b[c]);
        }
        *(u16x4*)(out + (long)row * 192 + lane * 4) = o;
    } else if (lane < 48) {
        u16x4 z = {0, 0, 0, 0};
        *(u16x4*)(out + (long)row * 192 + 180 + (lane - 45) * 4) = z;
    }
}

// ---------------------------------------------------------------------------
// A-resident GEMM (r13): 128-row panel, 48KB LDS, 4 waves 2x2, acc[4][2],
// z-split col-groups, fragment-major B. EPI: 0=qkv (V direct into vP),
// 1=proj(+bias+f32 resid->bf16).
// ---------------------------------------------------------------------------
template<int KTOT, int NCB, int EPI>
__global__ __launch_bounds__(256)
void gemm_k(const u16* __restrict__ A, const u16* __restrict__ BtF,
            const float* __restrict__ bias, const float* __restrict__ resid,
            void* __restrict__ o0, void* __restrict__ o1, void* __restrict__ o2)
{
    constexpr int NKT = KTOT / 32;
    __shared__ u16 lds_a[128 * 192];           // 48 KB
    const int tid = threadIdx.x;
    const int l = tid & 63, wv = tid >> 6;
    const int wm = wv >> 1, wn = wv & 1;
    const int l15 = l & 15, lg = l >> 4;
    const int rx7 = l15 & 7;
    const long rowb = (long)blockIdx.x * 128;
    const int cb0 = blockIdx.y * NCB;
    const f32x4 fz = {0.f, 0.f, 0.f, 0.f};

    f32x4 acc[4][2];
    #pragma unroll
    for (int i = 0; i < 4; i++) { acc[i][0] = fz; acc[i][1] = fz; }

    const u16* aptr[4];
    #pragma unroll
    for (int mi = 0; mi < 4; mi++)
        aptr[mi] = lds_a + (wm * 64 + mi * 16 + l15) * 192;

    auto epilogue = [&](int cb, f32x4 (&ac)[4][2]) {
        #pragma unroll
        for (int nd = 0; nd < 2; nd++) {
            const int c = cb * 64 + wn * 32 + nd * 16 + l15;
            if (EPI == 0) {
                if (c < 540) {
                    const float bb = bias[c];
                    const int sec = (c >= 360) ? 2 : ((c >= 180) ? 1 : 0);
                    const int cc = c - sec * 180;
                    const int hh = cc / 30, d = cc - hh * 30;
                    #pragma unroll
                    for (int mi = 0; mi < 4; mi++) {
                        const long t0 = rowb + wm * 64 + mi * 16 + lg * 4;
                        const int y = (int)(t0 >> 8), x0 = (int)(t0 & 255);
                        if (sec == 0) {
                            int win = ((y >> 4) << 4) | (x0 >> 4);
                            int qrow0 = ((y & 15) << 4) | (x0 & 15);
                            u16* dst = (u16*)o0 + (((long)(win * 6 + hh)) * 256 + qrow0) * 32 + d;
                            #pragma unroll
                            for (int rr = 0; rr < 4; rr++)
                                dst[rr * 32] = f2bf((ac[mi][nd][rr] + bb) * SCALE_Q2);
                        } else if (sec == 1) {
                            u16* dst = (u16*)o1 + (((long)hh * 264 + y + 4) * 264 + x0 + 4) * 32 + d;
                            #pragma unroll
                            for (int rr = 0; rr < 4; rr++)
                                dst[rr * 32] = f2bf(ac[mi][nd][rr] + bb);
                        } else {
                            long dstoff = (((long)hh * 32 + d) * 264 + y + 4) * 272 + x0 + 4;
                            union { u16x4 v4; unsigned u2[2]; } pv;
                            pv.u2[0] = pk_bf16(ac[mi][nd][0] + bb, ac[mi][nd][1] + bb);
                            pv.u2[1] = pk_bf16(ac[mi][nd][2] + bb, ac[mi][nd][3] + bb);
                            *(u16x4*)((u16*)o2 + dstoff) = pv.v4;
                        }
                    }
                }
            } else {
                if (c < 180) {
                    const float bb = bias[c];
                    #pragma unroll
                    for (int mi = 0; mi < 4; mi++) {
                        const long t0 = rowb + wm * 64 + mi * 16 + lg * 4;
                        const float* rs = resid + t0 * 180 + c;
                        u16* dst = (u16*)o0 + t0 * 192 + c;
                        #pragma unroll
                        for (int rr = 0; rr < 4; rr++)
                            dst[rr * 192] = f2bf(ac[mi][nd][rr] + bb + rs[rr * 180]);
                    }
                }
            }
        }
    };

    #pragma unroll
    for (int R = 0; R < 12; ++R) {             // stage A: 128 rows x 24 granules
        int idx = R * 256 + tid;
        int row = idx / 24, gp = idx - row * 24;
        int g = (gp & 24) | ((gp & 7) ^ (row & 7));
        GLD16(A + (rowb + row) * KTOT + g * 8,
              (char*)lds_a + R * 4096 + wv * 1024);
    }
    __syncthreads();

    #pragma unroll
    for (int icb = 0; icb < NCB; ++icb) {
        const u16* Bf = BtF + ((long)((cb0 + icb) * 4 + wn * 2) * NKT) * 512 + l * 8;
        #pragma unroll
        for (int kg = 0; kg < 6; kg += 3) {
            bf16x8 bfr[2][3];
            #pragma unroll
            for (int g2 = 0; g2 < 3; ++g2) {
                bfr[0][g2] = *(const bf16x8*)(Bf + (kg + g2) * 512);
                bfr[1][g2] = *(const bf16x8*)(Bf + (NKT + kg + g2) * 512);
            }
            #pragma unroll
            for (int g2 = 0; g2 < 3; ++g2) {
                const int k = kg + g2;
                const int gk = k * 4 + lg;
                const int gpk = (gk & 24) | ((gk & 7) ^ rx7);
                bf16x8 af[4];
                #pragma unroll
                for (int mi = 0; mi < 4; mi++)
                    af[mi] = *(const bf16x8*)(aptr[mi] + gpk * 8);
                #pragma unroll
                for (int mi = 0; mi < 4; mi++)
                    #pragma unroll
                    for (int nd = 0; nd < 2; nd++)
                        acc[mi][nd] = __builtin_amdgcn_mfma_f32_16x16x32_bf16(af[mi], bfr[nd][g2], acc[mi][nd], 0, 0, 0);
            }
        }
        epilogue(cb0 + icb, acc);
        #pragma unroll
        for (int i = 0; i < 4; i++) { acc[i][0] = fz; acc[i][1] = fz; }
    }
}

// ---------------------------------------------------------------------------
// Fused MLP: fc1 (gelu) -> LDS H tile -> fc2 (+bias+bf16 resid -> f32 out).
// 64-row panel; A 24KB + H 48KB = 72KB LDS. Wave tile 64x16 (acc[4][1],
// 4 MFMA per B-load). H stored with XOR-group swizzle so fc2's b128
// A-fragment reads are conflict-light. No global h1 traffic at all.
// ---------------------------------------------------------------------------
__global__ __launch_bounds__(256)
void mlp_k(const u16* __restrict__ A, const u16* __restrict__ fc1T,
           const u16* __restrict__ fc2T, const float* __restrict__ b1,
           const float* __restrict__ b2, const u16* __restrict__ resid,
           float* __restrict__ out)
{
    __shared__ u16 lds_a[64 * 192];    // 24 KB
    __shared__ u16 H[64 * 384];        // 48 KB
    const int tid = threadIdx.x;
    const int l = tid & 63, wv = tid >> 6;
    const int l15 = l & 15, lg = l >> 4;
    const int rx7 = l15 & 7;
    const long rowb = (long)blockIdx.x * 64;
    const f32x4 fz = {0.f, 0.f, 0.f, 0.f};

    // stage A (64 x 192): 1536 granules / 256 threads = 6 rounds
    #pragma unroll
    for (int R = 0; R < 6; ++R) {
        int idx = R * 256 + tid;
        int row = idx / 24, gp = idx - row * 24;
        int g = (gp & 24) | ((gp & 7) ^ (row & 7));
        GLD16(A + (rowb + row) * 192 + g * 8, (char*)lds_a + R * 4096 + wv * 1024);
    }
    __syncthreads();

    const u16* aptr[4];
    #pragma unroll
    for (int mi = 0; mi < 4; mi++)
        aptr[mi] = lds_a + (mi * 16 + l15) * 192;

    // ---- fc1 phase: 6 col-blocks of 64, gelu -> H ----
    #pragma unroll
    for (int cb = 0; cb < 6; ++cb) {
        f32x4 ac[4] = {fz, fz, fz, fz};
        const u16* Bf = fc1T + ((long)(cb * 4 + wv) * 6) * 512 + l * 8;
        #pragma unroll
        for (int k = 0; k < 6; ++k) {
            bf16x8 bfr = *(const bf16x8*)(Bf + k * 512);
            const int gk = k * 4 + lg;
            const int gpk = (gk & 24) | ((gk & 7) ^ rx7);
            bf16x8 af[4];
            #pragma unroll
            for (int mi = 0; mi < 4; mi++)
                af[mi] = *(const bf16x8*)(aptr[mi] + gpk * 8);
            #pragma unroll
            for (int mi = 0; mi < 4; mi++)
                ac[mi] = __builtin_amdgcn_mfma_f32_16x16x32_bf16(af[mi], bfr, ac[mi], 0, 0, 0);
        }
        const int c = cb * 64 + wv * 16 + l15;
        const float bb = (c < 360) ? b1[c] : 0.f;
        const int gC = c >> 3, cL = c & 7;
        #pragma unroll
        for (int mi = 0; mi < 4; mi++) {
            #pragma unroll
            for (int rr = 0; rr < 4; rr++) {
                int row = mi * 16 + lg * 4 + rr;
                float xx = ac[mi][rr] + bb;
                float u2n = -2.f * xx * (0.7978845608f + 0.0356774081f * xx * xx);
                float ge = xx / (1.f + __expf(u2n));
                int gS = (gC & ~7) | ((gC & 7) ^ (row & 7));
                H[row * 384 + gS * 8 + cL] = f2bf(ge);
            }
        }
    }
    __syncthreads();

    // ---- fc2 phase: K=384 from LDS H, 3 col-blocks of 64 ----
    #pragma unroll
    for (int cb = 0; cb < 3; ++cb) {
        f32x4 ac[4] = {fz, fz, fz, fz};
        const u16* Bf = fc2T + ((long)(cb * 4 + wv) * 12) * 512 + l * 8;
        #pragma unroll
        for (int k = 0; k < 12; ++k) {
            bf16x8 bfr = *(const bf16x8*)(Bf + k * 512);
            const int gk = k * 4 + lg;
            const int gS = (gk & ~7) | ((gk & 7) ^ rx7);   // row&7 == rx7
            bf16x8 af[4];
            #pragma unroll
            for (int mi = 0; mi < 4; mi++)
                af[mi] = *(const bf16x8*)(H + (mi * 16 + l15) * 384 + gS * 8);
            #pragma unroll
            for (int mi = 0; mi < 4; mi++)
                ac[mi] = __builtin_amdgcn_mfma_f32_16x16x32_bf16(af[mi], bfr, ac[mi], 0, 0, 0);
        }
        const int c = cb * 64 + wv * 16 + l15;
        if (c < 180) {
            const float bb = b2[c];
            #pragma unroll
            for (int mi = 0; mi < 4; mi++) {
                const long t0 = rowb + mi * 16 + lg * 4;
                const u16* rs = resid + t0 * 192 + c;
                float* dst = out + t0 * 180 + c;
                #pragma unroll
                for (int rr = 0; rr < 4; rr++)
                    dst[rr * 180] = ac[mi][rr] + bb + bf2f(rs[rr * 192]);
            }
        }
    }
}

// ---------------------------------------------------------------------------
// Attention (r13, unchanged): block=(window,head), 4 waves x 64 q, 9 chunks.
// ---------------------------------------------------------------------------
__global__ __launch_bounds__(256)
void attn_k(const u16* __restrict__ q_g, const u16* __restrict__ K_pad,
            const u16* __restrict__ vP, const u16* __restrict__ bias5,
            u16* __restrict__ attn_out)
{
    __shared__ u16 kc[2][64 * 32];
    __shared__ u16 vt[2][32 * 64];

    const int w = ((blockIdx.x & 7) << 5) | (blockIdx.x >> 3);   // XCD swizzle
    const int h = blockIdx.y;
    const int wy = w >> 4, wx = w & 15;
    const int tid = threadIdx.x;
    const int wv = tid >> 6, l = tid & 63;
    const int l15 = l & 15, lg = l >> 4;
    const int swzk = (l15 >> 1) & 3;
    const int swzv = l15 & 7;

    bf16x8 qb[4];
    #pragma unroll
    for (int ni = 0; ni < 4; ni++) {
        int qrow = wv * 64 + ni * 16 + l15;
        qb[ni] = *(const bf16x8*)(q_g + (((long)(w * 6 + h)) * 256 + qrow) * 32 + lg * 8);
    }

    f32x4 acc[2][4];
    #pragma unroll
    for (int i = 0; i < 2; i++)
        #pragma unroll
        for (int j = 0; j < 4; j++) acc[i][j] = (f32x4){0.f, 0.f, 0.f, 0.f};

    const int tK = tid >> 2;
    const int gtk = (l & 3) ^ ((l >> 3) & 3);
    const int aK = (tK >= 48) ? 2 : (tK >= 24 ? 1 : 0);
    const int bK = tK - aK * 24;
    const u16* KbaseRow = K_pad + (((long)(h * 264 + wy * 16)) * 264 + wx * 16) * 32 + gtk * 8;
    const int dV = tid >> 3;
    const int gtv = (l & 7) ^ (l >> 3);
    const int aV = gtv / 3, bV = (gtv % 3) * 8;
    const u16* Vrow0 = vP + ((((long)h * 32 + dV) * 264) + wy * 16) * 272 + wx * 16;
    const u16* Bp = bias5 + (long)h * 147456 + ((lg * 4 + wv) * 16 + l15) * 16;

    GLD16(KbaseRow + ((long)aK * 264 + bK) * 32, (char*)kc[0] + wv * 1024);
    GLD16(Vrow0 + aV * 272 + bV, (char*)vt[0] + wv * 1024);

    u16x8 bl[4], bh[4];
    #pragma unroll
    for (int mi = 0; mi < 4; mi++) {
        bl[mi] = *(const u16x8*)(Bp + mi * 4096);
        bh[mi] = *(const u16x8*)(Bp + mi * 4096 + 8);
    }

    #pragma unroll
    for (int ch = 0; ch < 9; ++ch) {
        __syncthreads();
        u16x8 bln[4], bhn[4];
        if (ch < 8) {   // prefetch chunk ch+1: K, V, bias
            int n = (ch + 1) * 64;
            int c1 = n / 24, c2 = n - c1 * 24;
            int bb2 = bK + c2;
            int t2 = bb2 >= 24;
            int oy = c1 + aK + t2, ox = bb2 - (t2 ? 24 : 0);
            GLD16(KbaseRow + ((long)oy * 264 + ox) * 32, (char*)kc[(ch + 1) & 1] + wv * 1024);
            int bbv = bV + c2;
            int t2v = bbv >= 24;
            int oyv = c1 + aV + t2v, oxv = bbv - (t2v ? 24 : 0);
            GLD16(Vrow0 + oyv * 272 + oxv, (char*)vt[(ch + 1) & 1] + wv * 1024);
            #pragma unroll
            for (int mi = 0; mi < 4; mi++) {
                bln[mi] = *(const u16x8*)(Bp + ((ch + 1) * 4 + mi) * 4096);
                bhn[mi] = *(const u16x8*)(Bp + ((ch + 1) * 4 + mi) * 4096 + 8);
            }
        }
        const u16* kcur = kc[ch & 1];
        const u16* vcur = vt[ch & 1];

        #pragma unroll
        for (int ks = 0; ks < 2; ++ks) {
            int Wp[2][4][2];
            #pragma unroll
            for (int mih = 0; mih < 2; ++mih) {
                int mi = ks * 2 + mih;
                int key = ks * 32 + mih * 16 + l15;
                bf16x8 ka = *(const bf16x8*)(kcur + key * 32 + (lg ^ swzk) * 8);
                union { u16x8 v; unsigned d[4]; } ulo, uhi;
                ulo.v = bl[mi]; uhi.v = bh[mi];
                f32x4 s[4];
                #pragma unroll
                for (int ni = 0; ni < 4; ni++) {
                    unsigned dA = (ni < 2) ? ulo.d[(ni & 1) * 2]     : uhi.d[(ni & 1) * 2];
                    unsigned dB = (ni < 2) ? ulo.d[(ni & 1) * 2 + 1] : uhi.d[(ni & 1) * 2 + 1];
                    f32x4 ci;
                    ci[0] = __uint_as_float(dA << 16);
                    ci[1] = __uint_as_float(dA & 0xFFFF0000u);
                    ci[2] = __uint_as_float(dB << 16);
                    ci[3] = __uint_as_float(dB & 0xFFFF0000u);
                    s[ni] = ci;
                }
                #pragma unroll
                for (int ni = 0; ni < 4; ni++)
                    s[ni] = __builtin_amdgcn_mfma_f32_16x16x32_bf16(ka, qb[ni], s[ni], 0, 0, 0);
                #pragma unroll
                for (int ni = 0; ni < 4; ni++) {
                    float p0 = exp2_raw(s[ni][0]);
                    float p1 = exp2_raw(s[ni][1]);
                    float p2 = exp2_raw(s[ni][2]);
                    float p3 = exp2_raw(s[ni][3]);
                    Wp[mih][ni][0] = (int)pk_bf16(p0, p1);
                    Wp[mih][ni][1] = (int)pk_bf16(p2, p3);
                }
            }
            bf16x8 va0 = *(const bf16x8*)(vcur + l15 * 64 + ((ks * 4 + lg) ^ swzv) * 8);
            bf16x8 va1 = *(const bf16x8*)(vcur + (16 + l15) * 64 + ((ks * 4 + lg) ^ swzv) * 8);
            #pragma unroll
            for (int ni = 0; ni < 4; ni++) {
                i32x2 r0 = __builtin_amdgcn_permlane32_swap(Wp[0][ni][0], Wp[1][ni][0], false, false);
                i32x2 r1 = __builtin_amdgcn_permlane32_swap(Wp[0][ni][1], Wp[1][ni][1], false, false);
                int wd0, wd1, wd2, wd3;
                xswap16(r0[0], r0[1], wd0, wd2);
                xswap16(r1[0], r1[1], wd1, wd3);
                union { int wd[4]; bf16x8 v; } pu;
                pu.wd[0] = wd0; pu.wd[1] = wd1; pu.wd[2] = wd2; pu.wd[3] = wd3;
                acc[0][ni] = __builtin_amdgcn_mfma_f32_16x16x32_bf16(va0, pu.v, acc[0][ni], 0, 0, 0);
                acc[1][ni] = __builtin_amdgcn_mfma_f32_16x16x32_bf16(va1, pu.v, acc[1][ni], 0, 0, 0);
            }
        }
        if (ch < 8) {
            #pragma unroll
            for (int mi = 0; mi < 4; mi++) { bl[mi] = bln[mi]; bh[mi] = bhn[mi]; }
        }
    }

    #pragma unroll
    for (int ni = 0; ni < 4; ni++) {
        float sum = __shfl(acc[1][ni][2], 48 + l15);
        float inv = 1.f / sum;
        int q = wv * 64 + ni * 16 + l15;
        int y = wy * 16 + (q >> 4), x = wx * 16 + (q & 15);
        u16* bp = attn_out + ((long)(y * 256 + x)) * 192 + h * 30;
        unsigned w0 = pk_bf16(acc[0][ni][0] * inv, acc[0][ni][1] * inv);
        unsigned w1 = pk_bf16(acc[0][ni][2] * inv, acc[0][ni][3] * inv);
        *(unsigned*)(bp + lg * 4)     = w0;
        *(unsigned*)(bp + lg * 4 + 2) = w1;
        unsigned w2 = pk_bf16(acc[1][ni][0] * inv, acc[1][ni][1] * inv);
        if (lg < 3) {
            unsigned w3 = pk_bf16(acc[1][ni][2] * inv, acc[1][ni][3] * inv);
            *(unsigned*)(bp + 16 + lg * 4)     = w2;
            *(unsigned*)(bp + 16 + lg * 4 + 2) = w3;
        } else {
            *(unsigned*)(bp + 28) = w2;
        }
    }
}

// ---------------------------------------------------------------------------
extern "C" void kernel_launch(void* const* d_in, const int* in_sizes, int n_in,
                              void* d_out, int out_size, void* d_ws, size_t ws_size,
                              hipStream_t stream)
{
    (void)in_sizes; (void)n_in; (void)out_size; (void)ws_size;
    const float* x      = (const float*)d_in[0];
    const int*   rpi    = (const int*)d_in[1];
    const float* n1w    = (const float*)d_in[2];
    const float* n1b    = (const float*)d_in[3];
    const float* qkv_w  = (const float*)d_in[4];
    const float* qkv_b  = (const float*)d_in[5];
    const float* rpb    = (const float*)d_in[6];
    const float* proj_w = (const float*)d_in[7];
    const float* proj_b = (const float*)d_in[8];
    const float* n2w    = (const float*)d_in[9];
    const float* n2b    = (const float*)d_in[10];
    const float* fc1_w  = (const float*)d_in[11];
    const float* fc1_b  = (const float*)d_in[12];
    const float* fc2_w  = (const float*)d_in[13];
    const float* fc2_b  = (const float*)d_in[14];
    float* out = (float*)d_out;

    char* ws = (char*)d_ws;
    size_t off = 0;
    auto alloc = [&](size_t bytes) -> void* {
        void* p = ws + off; off += (bytes + 511) & ~(size_t)511; return p;
    };
    u16*   xn     = (u16*)alloc(65536ull * 192 * 2);        // ln out; ao aliases
    u16*   q_g    = (u16*)alloc(65536ull * 192 * 2);        // [win][h][q][32]
    u16*   K_pad  = (u16*)alloc(6ull * 264 * 264 * 32 * 2); // [h][y][x][32]
    u16*   x2b    = (u16*)alloc(65536ull * 192 * 2);        // bf16 resid stream
    u16*   vP     = (u16*)alloc(6ull * 32 * 264 * 272 * 2); // [h][d][y+4][x+4]
    u16*   bias5  = (u16*)alloc(6ull * 36 * 4 * 4 * 16 * 16 * 2);
    u16*   qkvT   = (u16*)alloc(640ull * 192 * 2);
    u16*   projT  = (u16*)alloc(256ull * 192 * 2);
    u16*   fc1T   = (u16*)alloc(384ull * 192 * 2);
    u16*   fc2T   = (u16*)alloc(256ull * 384 * 2);
    u16*   ao     = xn;    // ln1 zero-fills cols 180..191; attn fills 0..179
    u16*   xn2    = q_g;   // ln2 out reuses q_g (dead after attn)

    prepln_k<<<dim3(28168), dim3(256), 0, stream>>>(x, n1w, n1b, xn,
        qkv_w, proj_w, fc1_w, fc2_w, rpi, rpb,
        qkvT, projT, fc1T, fc2T, bias5, (unsigned*)K_pad, (unsigned*)vP);
    gemm_k<192, 3, 0><<<dim3(512, 3), dim3(256), 0, stream>>>(
        xn, qkvT, qkv_b, (const float*)nullptr, q_g, K_pad, vP);
    attn_k<<<dim3(256, 6), dim3(256), 0, stream>>>(q_g, K_pad, vP, bias5, ao);
    gemm_k<192, 3, 1><<<dim3(512, 1), dim3(256), 0, stream>>>(
        ao, projT, proj_b, x, x2b, nullptr, nullptr);
    lnb_k<<<dim3(16384), dim3(256), 0, stream>>>(x2b, n2w, n2b, xn2);
    mlp_k<<<dim3(1024), dim3(256), 0, stream>>>(
        xn2, fc1T, fc2T, fc1_b, fc2_b, x2b, out);
}

// Round 15
// 209.428 us; speedup vs baseline: 1.5221x; 1.0442x over previous
//
#include <hip/hip_runtime.h>

typedef float f32x4 __attribute__((ext_vector_type(4)));
typedef float fvec4 __attribute__((ext_vector_type(4)));
typedef __bf16 bf16x8 __attribute__((ext_vector_type(8)));
typedef unsigned short u16;
typedef u16 u16x8 __attribute__((ext_vector_type(8)));
typedef u16 u16x4 __attribute__((ext_vector_type(4)));
typedef int i32x2 __attribute__((ext_vector_type(2)));

#define SCALE_Q 0.18257418583505536f   /* 30^-0.5 */
#define LOG2E   1.4426950408889634f
#define SCALE_Q2 (SCALE_Q * LOG2E)     /* folded: exp(s) = 2^(s*log2e) */

__device__ __forceinline__ u16 f2bf(float f) {
    union { __bf16 h; u16 u; } cv; cv.h = (__bf16)f; return cv.u;
}
__device__ __forceinline__ float bf2f(u16 u) {
    union { __bf16 h; u16 u; } cv; cv.u = u; return (float)cv.h;
}
__device__ __forceinline__ float exp2_raw(float x) {
    float r;
    asm("v_exp_f32 %0, %1" : "=v"(r) : "v"(x));
    return r;
}
__device__ __forceinline__ unsigned pk_bf16(float a, float b) {
    unsigned r;
    asm("v_cvt_pk_bf16_f32 %0, %1, %2" : "=v"(r) : "v"(a), "v"(b));
    return r;
}

// async global->LDS, 16B per lane; LDS dest = wave-uniform base + lane*16
#define GLD16(gsrc, ldst) __builtin_amdgcn_global_load_lds( \
    (const __attribute__((address_space(1))) unsigned*)(gsrc), \
    (__attribute__((address_space(3))) unsigned*)(ldst), 16, 0, 0)

// lane^16 cross-exchange pair
__device__ __forceinline__ void xswap16(int a, int b, int& u, int& v) {
#if __has_builtin(__builtin_amdgcn_permlane16_swap)
    i32x2 r = __builtin_amdgcn_permlane16_swap(a, b, false, false);
    u = r[0]; v = r[1];
#else
    int sa = __builtin_amdgcn_ds_swizzle(a, 0x401F);
    int sb = __builtin_amdgcn_ds_swizzle(b, 0x401F);
    bool hi = (threadIdx.x & 16) != 0;
    u = hi ? sb : a;
    v = hi ? b : sa;
#endif
}

// ---------------------------------------------------------------------------
// prep + ln1 merged. Weights fragment-major: BtF[ng][k][lane][8].
// projT rows use PADDED-k mapping (k' = h*32+d; rows with d>=30 are zero)
// to match the new ao[t][h*32+d] layout.
// ---------------------------------------------------------------------------
__device__ __forceinline__ void border_yx(int i, int& y, int& x) {
    if (i < 1056)      { y = i / 264; x = i % 264; }
    else if (i < 2112) { int j = i - 1056; y = 260 + j / 264; x = j % 264; }
    else               { int j = i - 2112; y = 4 + (j >> 3); int xx = j & 7;
                         x = (xx < 4) ? xx : 256 + xx; }
}

__global__ __launch_bounds__(256)
void prepln_k(const float* __restrict__ x, const float* __restrict__ n1w,
              const float* __restrict__ n1b, u16* __restrict__ xn,
              const float* __restrict__ qkv_w, const float* __restrict__ proj_w,
              const float* __restrict__ fc1_w, const float* __restrict__ fc2_w,
              const int* __restrict__ rpi, const float* __restrict__ rpb,
              u16* __restrict__ qkvT, u16* __restrict__ projT,
              u16* __restrict__ fc1T, u16* __restrict__ fc2T,
              u16* __restrict__ bias5, unsigned* __restrict__ kp_u32,
              unsigned* __restrict__ vp_u32)
{
    if (blockIdx.x < 16384) {      // ----- LayerNorm1 -----
        int row = blockIdx.x * 4 + (threadIdx.x >> 6);
        int lane = threadIdx.x & 63;
        fvec4 v = {0.f, 0.f, 0.f, 0.f};
        if (lane < 45) v = *(const fvec4*)(x + (long)row * 180 + lane * 4);
        float s  = v.x + v.y + v.z + v.w;
        float sq = v.x * v.x + v.y * v.y + v.z * v.z + v.w * v.w;
        for (int m = 1; m < 64; m <<= 1) { s += __shfl_xor(s, m); sq += __shfl_xor(sq, m); }
        float mean = s * (1.f / 180.f);
        float var  = sq * (1.f / 180.f) - mean * mean;
        float rstd = rsqrtf(var + 1e-5f);
        if (lane < 45) {
            u16x4 o;
            #pragma unroll
            for (int j = 0; j < 4; j++) {
                int c = lane * 4 + j;
                o[j] = f2bf((v[j] - mean) * rstd * n1w[c] + n1b[c]);
            }
            *(u16x4*)(xn + (long)row * 192 + lane * 4) = o;
        } else if (lane < 48) {
            u16x4 z = {0, 0, 0, 0};
            *(u16x4*)(xn + (long)row * 192 + 180 + (lane - 45) * 4) = z;
        }
        return;
    }
    int idx = (blockIdx.x - 16384) * 256 + threadIdx.x;
    if (idx < 122880) {                        // qkvT frag-major: 40 ng x 6 k
        int e = idx & 7, l15b = (idx >> 3) & 15, lgb = (idx >> 7) & 3;
        int kstep = (idx >> 9) % 6, ng = idx / 3072;
        int col = ng * 16 + l15b, kd = kstep * 32 + lgb * 8 + e;
        qkvT[idx] = (col < 540 && kd < 180) ? f2bf(qkv_w[kd * 540 + col]) : (u16)0;
    } else if (idx < 172032) {                 // projT frag-major, padded-k rows
        int i = idx - 122880;
        int e = i & 7, l15b = (i >> 3) & 15, lgb = (i >> 7) & 3;
        int kstep = (i >> 9) % 6, ng = i / 3072;
        int col = ng * 16 + l15b, kdp = kstep * 32 + lgb * 8 + e;
        int sub = kdp & 31;
        int k = (kdp >> 5) * 30 + sub;
        projT[i] = (col < 180 && sub < 30) ? f2bf(proj_w[k * 180 + col]) : (u16)0;
    } else if (idx < 245760) {                 // fc1T frag-major: 24 ng x 6 k
        int i = idx - 172032;
        int e = i & 7, l15b = (i >> 3) & 15, lgb = (i >> 7) & 3;
        int kstep = (i >> 9) % 6, ng = i / 3072;
        int col = ng * 16 + l15b, kd = kstep * 32 + lgb * 8 + e;
        fc1T[i] = (col < 360 && kd < 180) ? f2bf(fc1_w[kd * 360 + col]) : (u16)0;
    } else if (idx < 344064) {                 // fc2T frag-major: 12 ng x 12 k
        int i = idx - 245760;
        int e = i & 7, l15b = (i >> 3) & 15, lgb = (i >> 7) & 3;
        int kstep = (i >> 9) % 12, ng = i / 6144;
        int col = ng * 16 + l15b, kd = kstep * 32 + lgb * 8 + e;
        fc2T[i] = (col < 180 && kd < 360) ? f2bf(fc2_w[kd * 180 + col]) : (u16)0;
    } else if (idx < 1228800) {                // bias5[(h*36+ch*4+mi)][lg][wv][l15][e]
        int i = idx - 344064;
        int e = i & 15, l15 = (i >> 4) & 15, wv2 = (i >> 8) & 3, lg2 = (i >> 10) & 3;
        int cm36 = i >> 12;
        int hh = cm36 / 36, cm = cm36 % 36;
        int ch = cm >> 2, mi = cm & 3;
        int ni = e >> 2, rr = e & 3;
        int q = wv2 * 64 + ni * 16 + l15;
        int key = ch * 64 + mi * 16 + lg2 * 4 + rr;
        bias5[i] = f2bf(rpb[rpi[q * 576 + key] * 6 + hh] * LOG2E);
    } else if (idx < 1628160) {                // K_pad border tokens (u32 x16)
        int i = idx - 1228800;
        int tok = i >> 4, wj = i & 15;
        int h = tok / 4160, b = tok % 4160, y, xx;
        border_yx(b, y, xx);
        kp_u32[((h * 264 + y) * 264 + xx) * 16 + wj] = 0u;
    } else if (idx < 2021376) {                // K_pad interior dims 30,31
        int i = idx - 1628160;
        int h = i / 65536, t = i % 65536;
        int y = t >> 8, xx = t & 255;
        kp_u32[((h * 264 + y + 4) * 264 + xx + 4) * 16 + 15] = 0u;
    } else if (idx < 2236800) {                // vP d=30 plane := 1.0
        int i = idx - 2021376;
        int h = i / 35904, r = i % 35904;
        vp_u32[(h * 32 + 30) * 35904 + r] = 0x3F803F80u;
    } else if (idx < 2452224) {                // vP d=31 plane := 0
        int i = idx - 2236800;
        int h = i / 35904, r = i % 35904;
        vp_u32[(h * 32 + 31) * 35904 + r] = 0u;
    } else if (idx < 3016704) {                // vP d<30 borders := 0
        int i = idx - 2452224;
        int hd = i / 3136, j = i % 3136;
        int h = hd / 30, d = hd % 30;
        int y, xu;
        if (j < 1088) { int r = j / 136; y = r + (r >= 4 ? 256 : 0); xu = j % 136; }
        else { int j2 = j - 1088; y = 4 + (j2 >> 3); int q = j2 & 7;
               xu = (q < 2) ? q : 128 + q; }
        vp_u32[((h * 32 + d) * 264 + y) * 136 + xu] = 0u;
    }
}

// ---------------------------------------------------------------------------
// A-resident GEMM (r13): 128-row panel, 48KB LDS, 4 waves 2x2, acc[4][2],
// z-split col-groups, fragment-major B. EPI: 0=qkv (V direct into vP),
// 1=proj(+bias+f32 resid->bf16 x2b; zero-fills x2b cols 180..191).
// ---------------------------------------------------------------------------
template<int KTOT, int NCB, int EPI>
__global__ __launch_bounds__(256)
void gemm_k(const u16* __restrict__ A, const u16* __restrict__ BtF,
            const float* __restrict__ bias, const float* __restrict__ resid,
            void* __restrict__ o0, void* __restrict__ o1, void* __restrict__ o2)
{
    constexpr int NKT = KTOT / 32;
    __shared__ u16 lds_a[128 * 192];           // 48 KB
    const int tid = threadIdx.x;
    const int l = tid & 63, wv = tid >> 6;
    const int wm = wv >> 1, wn = wv & 1;
    const int l15 = l & 15, lg = l >> 4;
    const int rx7 = l15 & 7;
    const long rowb = (long)blockIdx.x * 128;
    const int cb0 = blockIdx.y * NCB;
    const f32x4 fz = {0.f, 0.f, 0.f, 0.f};

    f32x4 acc[4][2];
    #pragma unroll
    for (int i = 0; i < 4; i++) { acc[i][0] = fz; acc[i][1] = fz; }

    const u16* aptr[4];
    #pragma unroll
    for (int mi = 0; mi < 4; mi++)
        aptr[mi] = lds_a + (wm * 64 + mi * 16 + l15) * 192;

    auto epilogue = [&](int cb, f32x4 (&ac)[4][2]) {
        #pragma unroll
        for (int nd = 0; nd < 2; nd++) {
            const int c = cb * 64 + wn * 32 + nd * 16 + l15;
            if (EPI == 0) {
                if (c < 540) {
                    const float bb = bias[c];
                    const int sec = (c >= 360) ? 2 : ((c >= 180) ? 1 : 0);
                    const int cc = c - sec * 180;
                    const int hh = cc / 30, d = cc - hh * 30;
                    #pragma unroll
                    for (int mi = 0; mi < 4; mi++) {
                        const long t0 = rowb + wm * 64 + mi * 16 + lg * 4;
                        const int y = (int)(t0 >> 8), x0 = (int)(t0 & 255);
                        if (sec == 0) {
                            int win = ((y >> 4) << 4) | (x0 >> 4);
                            int qrow0 = ((y & 15) << 4) | (x0 & 15);
                            u16* dst = (u16*)o0 + (((long)(win * 6 + hh)) * 256 + qrow0) * 32 + d;
                            #pragma unroll
                            for (int rr = 0; rr < 4; rr++)
                                dst[rr * 32] = f2bf((ac[mi][nd][rr] + bb) * SCALE_Q2);
                        } else if (sec == 1) {
                            u16* dst = (u16*)o1 + (((long)hh * 264 + y + 4) * 264 + x0 + 4) * 32 + d;
                            #pragma unroll
                            for (int rr = 0; rr < 4; rr++)
                                dst[rr * 32] = f2bf(ac[mi][nd][rr] + bb);
                        } else {
                            long dstoff = (((long)hh * 32 + d) * 264 + y + 4) * 272 + x0 + 4;
                            union { u16x4 v4; unsigned u2[2]; } pv;
                            pv.u2[0] = pk_bf16(ac[mi][nd][0] + bb, ac[mi][nd][1] + bb);
                            pv.u2[1] = pk_bf16(ac[mi][nd][2] + bb, ac[mi][nd][3] + bb);
                            *(u16x4*)((u16*)o2 + dstoff) = pv.v4;
                        }
                    }
                }
            } else {
                if (c < 180) {
                    const float bb = bias[c];
                    #pragma unroll
                    for (int mi = 0; mi < 4; mi++) {
                        const long t0 = rowb + wm * 64 + mi * 16 + lg * 4;
                        const float* rs = resid + t0 * 180 + c;
                        u16* dst = (u16*)o0 + t0 * 192 + c;
                        #pragma unroll
                        for (int rr = 0; rr < 4; rr++)
                            dst[rr * 192] = f2bf(ac[mi][nd][rr] + bb + rs[rr * 180]);
                    }
                } else {   // zero-fill pad cols 180..191 (enables LN2-in-mlp)
                    #pragma unroll
                    for (int mi = 0; mi < 4; mi++) {
                        const long t0 = rowb + wm * 64 + mi * 16 + lg * 4;
                        u16* dst = (u16*)o0 + t0 * 192 + c;
                        #pragma unroll
                        for (int rr = 0; rr < 4; rr++)
                            dst[rr * 192] = 0;
                    }
                }
            }
        }
    };

    #pragma unroll
    for (int R = 0; R < 12; ++R) {             // stage A: 128 rows x 24 granules
        int idx = R * 256 + tid;
        int row = idx / 24, gp = idx - row * 24;
        int g = (gp & 24) | ((gp & 7) ^ (row & 7));
        GLD16(A + (rowb + row) * KTOT + g * 8,
              (char*)lds_a + R * 4096 + wv * 1024);
    }
    __syncthreads();

    #pragma unroll
    for (int icb = 0; icb < NCB; ++icb) {
        const u16* Bf = BtF + ((long)((cb0 + icb) * 4 + wn * 2) * NKT) * 512 + l * 8;
        #pragma unroll
        for (int kg = 0; kg < 6; kg += 3) {
            bf16x8 bfr[2][3];
            #pragma unroll
            for (int g2 = 0; g2 < 3; ++g2) {
                bfr[0][g2] = *(const bf16x8*)(Bf + (kg + g2) * 512);
                bfr[1][g2] = *(const bf16x8*)(Bf + (NKT + kg + g2) * 512);
            }
            #pragma unroll
            for (int g2 = 0; g2 < 3; ++g2) {
                const int k = kg + g2;
                const int gk = k * 4 + lg;
                const int gpk = (gk & 24) | ((gk & 7) ^ rx7);
                bf16x8 af[4];
                #pragma unroll
                for (int mi = 0; mi < 4; mi++)
                    af[mi] = *(const bf16x8*)(aptr[mi] + gpk * 8);
                #pragma unroll
                for (int mi = 0; mi < 4; mi++)
                    #pragma unroll
                    for (int nd = 0; nd < 2; nd++)
                        acc[mi][nd] = __builtin_amdgcn_mfma_f32_16x16x32_bf16(af[mi], bfr[nd][g2], acc[mi][nd], 0, 0, 0);
            }
        }
        epilogue(cb0 + icb, acc);
        #pragma unroll
        for (int i = 0; i < 4; i++) { acc[i][0] = fz; acc[i][1] = fz; }
    }
}

// ---------------------------------------------------------------------------
// Fused MLP: stage x2b panel -> in-LDS LayerNorm2 -> fc1 (gelu) -> LDS H ->
// fc2 (+bias + bf16 resid -> f32 out). No global xn2 / h1 traffic.
// ---------------------------------------------------------------------------
__global__ __launch_bounds__(256)
void mlp_k(const u16* __restrict__ x2b, const u16* __restrict__ fc1T,
           const u16* __restrict__ fc2T, const float* __restrict__ b1,
           const float* __restrict__ b2, const float* __restrict__ n2w,
           const float* __restrict__ n2b, float* __restrict__ out)
{
    __shared__ u16 lds_a[64 * 192];    // 24 KB
    __shared__ u16 H[64 * 384];        // 48 KB
    const int tid = threadIdx.x;
    const int l = tid & 63, wv = tid >> 6;
    const int l15 = l & 15, lg = l >> 4;
    const int rx7 = l15 & 7;
    const long rowb = (long)blockIdx.x * 64;
    const f32x4 fz = {0.f, 0.f, 0.f, 0.f};

    // stage A (= x2b rows, 64 x 192)
    #pragma unroll
    for (int R = 0; R < 6; ++R) {
        int idx = R * 256 + tid;
        int row = idx / 24, gp = idx - row * 24;
        int g = (gp & 24) | ((gp & 7) ^ (row & 7));
        GLD16(x2b + (rowb + row) * 192 + g * 8, (char*)lds_a + R * 4096 + wv * 1024);
    }
    __syncthreads();

    // ---- LayerNorm2 in-LDS (4 threads/row; pad cols are zero => no mask) ----
    {
        const int row = tid >> 2, q = tid & 3;
        const int rw7 = row & 7;
        u16* rbase = lds_a + row * 192;
        u16x8 vals[6];
        float s = 0.f, sq = 0.f;
        #pragma unroll
        for (int j = 0; j < 6; ++j) {
            int g = q * 6 + j;
            int pg = (g & 24) | ((g & 7) ^ rw7);
            vals[j] = *(const u16x8*)(rbase + pg * 8);
            #pragma unroll
            for (int e = 0; e < 8; ++e) {
                float v = bf2f(vals[j][e]);
                s += v; sq += v * v;
            }
        }
        s  += __shfl_xor(s, 1);  sq += __shfl_xor(sq, 1);
        s  += __shfl_xor(s, 2);  sq += __shfl_xor(sq, 2);
        float mean = s * (1.f / 180.f);
        float var  = sq * (1.f / 180.f) - mean * mean;
        float rstd = rsqrtf(var + 1e-5f);
        #pragma unroll
        for (int j = 0; j < 6; ++j) {
            int g = q * 6 + j;
            int pg = (g & 24) | ((g & 7) ^ rw7);
            u16x8 o;
            #pragma unroll
            for (int e = 0; e < 8; ++e) {
                int c = g * 8 + e;
                int cc = (c < 180) ? c : 0;          // clamped index, no OOB
                float v = bf2f(vals[j][e]);
                float nv = (v - mean) * rstd * n2w[cc] + n2b[cc];
                o[e] = (c < 180) ? f2bf(nv) : (u16)0;
            }
            *(u16x8*)(rbase + pg * 8) = o;
        }
    }
    __syncthreads();

    const u16* aptr[4];
    #pragma unroll
    for (int mi = 0; mi < 4; mi++)
        aptr[mi] = lds_a + (mi * 16 + l15) * 192;

    // ---- fc1 phase: 6 col-blocks of 64, gelu -> H ----
    #pragma unroll
    for (int cb = 0; cb < 6; ++cb) {
        f32x4 ac[4] = {fz, fz, fz, fz};
        const u16* Bf = fc1T + ((long)(cb * 4 + wv) * 6) * 512 + l * 8;
        #pragma unroll
        for (int k = 0; k < 6; ++k) {
            bf16x8 bfr = *(const bf16x8*)(Bf + k * 512);
            const int gk = k * 4 + lg;
            const int gpk = (gk & 24) | ((gk & 7) ^ rx7);
            bf16x8 af[4];
            #pragma unroll
            for (int mi = 0; mi < 4; mi++)
                af[mi] = *(const bf16x8*)(aptr[mi] + gpk * 8);
            #pragma unroll
            for (int mi = 0; mi < 4; mi++)
                ac[mi] = __builtin_amdgcn_mfma_f32_16x16x32_bf16(af[mi], bfr, ac[mi], 0, 0, 0);
        }
        const int c = cb * 64 + wv * 16 + l15;
        const float bb = (c < 360) ? b1[c] : 0.f;
        const int gC = c >> 3, cL = c & 7;
        #pragma unroll
        for (int mi = 0; mi < 4; mi++) {
            #pragma unroll
            for (int rr = 0; rr < 4; rr++) {
                int row = mi * 16 + lg * 4 + rr;
                float xx = ac[mi][rr] + bb;
                float u2n = -2.f * xx * (0.7978845608f + 0.0356774081f * xx * xx);
                float ge = xx / (1.f + __expf(u2n));
                int gS = (gC & ~7) | ((gC & 7) ^ (row & 7));
                H[row * 384 + gS * 8 + cL] = f2bf(ge);
            }
        }
    }
    __syncthreads();

    // ---- fc2 phase: K=384 from LDS H, 3 col-blocks of 64 ----
    #pragma unroll
    for (int cb = 0; cb < 3; ++cb) {
        f32x4 ac[4] = {fz, fz, fz, fz};
        const u16* Bf = fc2T + ((long)(cb * 4 + wv) * 12) * 512 + l * 8;
        #pragma unroll
        for (int k = 0; k < 12; ++k) {
            bf16x8 bfr = *(const bf16x8*)(Bf + k * 512);
            const int gk = k * 4 + lg;
            const int gS = (gk & ~7) | ((gk & 7) ^ rx7);
            bf16x8 af[4];
            #pragma unroll
            for (int mi = 0; mi < 4; mi++)
                af[mi] = *(const bf16x8*)(H + (mi * 16 + l15) * 384 + gS * 8);
            #pragma unroll
            for (int mi = 0; mi < 4; mi++)
                ac[mi] = __builtin_amdgcn_mfma_f32_16x16x32_bf16(af[mi], bfr, ac[mi], 0, 0, 0);
        }
        const int c = cb * 64 + wv * 16 + l15;
        if (c < 180) {
            const float bb = b2[c];
            #pragma unroll
            for (int mi = 0; mi < 4; mi++) {
                const long t0 = rowb + mi * 16 + lg * 4;
                const u16* rs = x2b + t0 * 192 + c;
                float* dst = out + t0 * 180 + c;
                #pragma unroll
                for (int rr = 0; rr < 4; rr++)
                    dst[rr * 180] = ac[mi][rr] + bb + bf2f(rs[rr * 192]);
            }
        }
    }
}

// ---------------------------------------------------------------------------
// Attention: block=(window,head), 4 waves x 64 q, 9 chunks of 64 keys.
// Epilogue writes padded ao[t][h*32+d] -- each (t,h) is one full aligned
// 64B line (write amp 1x); dims 30,31 zeroed (projT pad rows are zero).
// ---------------------------------------------------------------------------
__global__ __launch_bounds__(256)
void attn_k(const u16* __restrict__ q_g, const u16* __restrict__ K_pad,
            const u16* __restrict__ vP, const u16* __restrict__ bias5,
            u16* __restrict__ attn_out)
{
    __shared__ u16 kc[2][64 * 32];
    __shared__ u16 vt[2][32 * 64];

    const int w = ((blockIdx.x & 7) << 5) | (blockIdx.x >> 3);   // XCD swizzle
    const int h = blockIdx.y;
    const int wy = w >> 4, wx = w & 15;
    const int tid = threadIdx.x;
    const int wv = tid >> 6, l = tid & 63;
    const int l15 = l & 15, lg = l >> 4;
    const int swzk = (l15 >> 1) & 3;
    const int swzv = l15 & 7;

    bf16x8 qb[4];
    #pragma unroll
    for (int ni = 0; ni < 4; ni++) {
        int qrow = wv * 64 + ni * 16 + l15;
        qb[ni] = *(const bf16x8*)(q_g + (((long)(w * 6 + h)) * 256 + qrow) * 32 + lg * 8);
    }

    f32x4 acc[2][4];
    #pragma unroll
    for (int i = 0; i < 2; i++)
        #pragma unroll
        for (int j = 0; j < 4; j++) acc[i][j] = (f32x4){0.f, 0.f, 0.f, 0.f};

    const int tK = tid >> 2;
    const int gtk = (l & 3) ^ ((l >> 3) & 3);
    const int aK = (tK >= 48) ? 2 : (tK >= 24 ? 1 : 0);
    const int bK = tK - aK * 24;
    const u16* KbaseRow = K_pad + (((long)(h * 264 + wy * 16)) * 264 + wx * 16) * 32 + gtk * 8;
    const int dV = tid >> 3;
    const int gtv = (l & 7) ^ (l >> 3);
    const int aV = gtv / 3, bV = (gtv % 3) * 8;
    const u16* Vrow0 = vP + ((((long)h * 32 + dV) * 264) + wy * 16) * 272 + wx * 16;
    const u16* Bp = bias5 + (long)h * 147456 + ((lg * 4 + wv) * 16 + l15) * 16;

    GLD16(KbaseRow + ((long)aK * 264 + bK) * 32, (char*)kc[0] + wv * 1024);
    GLD16(Vrow0 + aV * 272 + bV, (char*)vt[0] + wv * 1024);

    u16x8 bl[4], bh[4];
    #pragma unroll
    for (int mi = 0; mi < 4; mi++) {
        bl[mi] = *(const u16x8*)(Bp + mi * 4096);
        bh[mi] = *(const u16x8*)(Bp + mi * 4096 + 8);
    }

    #pragma unroll
    for (int ch = 0; ch < 9; ++ch) {
        __syncthreads();
        u16x8 bln[4], bhn[4];
        if (ch < 8) {   // prefetch chunk ch+1: K, V, bias
            int n = (ch + 1) * 64;
            int c1 = n / 24, c2 = n - c1 * 24;
            int bb2 = bK + c2;
            int t2 = bb2 >= 24;
            int oy = c1 + aK + t2, ox = bb2 - (t2 ? 24 : 0);
            GLD16(KbaseRow + ((long)oy * 264 + ox) * 32, (char*)kc[(ch + 1) & 1] + wv * 1024);
            int bbv = bV + c2;
            int t2v = bbv >= 24;
            int oyv = c1 + aV + t2v, oxv = bbv - (t2v ? 24 : 0);
            GLD16(Vrow0 + oyv * 272 + oxv, (char*)vt[(ch + 1) & 1] + wv * 1024);
            #pragma unroll
            for (int mi = 0; mi < 4; mi++) {
                bln[mi] = *(const u16x8*)(Bp + ((ch + 1) * 4 + mi) * 4096);
                bhn[mi] = *(const u16x8*)(Bp + ((ch + 1) * 4 + mi) * 4096 + 8);
            }
        }
        const u16* kcur = kc[ch & 1];
        const u16* vcur = vt[ch & 1];

        #pragma unroll
        for (int ks = 0; ks < 2; ++ks) {
            int Wp[2][4][2];
            #pragma unroll
            for (int mih = 0; mih < 2; ++mih) {
                int mi = ks * 2 + mih;
                int key = ks * 32 + mih * 16 + l15;
                bf16x8 ka = *(const bf16x8*)(kcur + key * 32 + (lg ^ swzk) * 8);
                union { u16x8 v; unsigned d[4]; } ulo, uhi;
                ulo.v = bl[mi]; uhi.v = bh[mi];
                f32x4 s[4];
                #pragma unroll
                for (int ni = 0; ni < 4; ni++) {
                    unsigned dA = (ni < 2) ? ulo.d[(ni & 1) * 2]     : uhi.d[(ni & 1) * 2];
                    unsigned dB = (ni < 2) ? ulo.d[(ni & 1) * 2 + 1] : uhi.d[(ni & 1) * 2 + 1];
                    f32x4 ci;
                    ci[0] = __uint_as_float(dA << 16);
                    ci[1] = __uint_as_float(dA & 0xFFFF0000u);
                    ci[2] = __uint_as_float(dB << 16);
                    ci[3] = __uint_as_float(dB & 0xFFFF0000u);
                    s[ni] = ci;
                }
                #pragma unroll
                for (int ni = 0; ni < 4; ni++)
                    s[ni] = __builtin_amdgcn_mfma_f32_16x16x32_bf16(ka, qb[ni], s[ni], 0, 0, 0);
                #pragma unroll
                for (int ni = 0; ni < 4; ni++) {
                    float p0 = exp2_raw(s[ni][0]);
                    float p1 = exp2_raw(s[ni][1]);
                    float p2 = exp2_raw(s[ni][2]);
                    float p3 = exp2_raw(s[ni][3]);
                    Wp[mih][ni][0] = (int)pk_bf16(p0, p1);
                    Wp[mih][ni][1] = (int)pk_bf16(p2, p3);
                }
            }
            bf16x8 va0 = *(const bf16x8*)(vcur + l15 * 64 + ((ks * 4 + lg) ^ swzv) * 8);
            bf16x8 va1 = *(const bf16x8*)(vcur + (16 + l15) * 64 + ((ks * 4 + lg) ^ swzv) * 8);
            #pragma unroll
            for (int ni = 0; ni < 4; ni++) {
                i32x2 r0 = __builtin_amdgcn_permlane32_swap(Wp[0][ni][0], Wp[1][ni][0], false, false);
                i32x2 r1 = __builtin_amdgcn_permlane32_swap(Wp[0][ni][1], Wp[1][ni][1], false, false);
                int wd0, wd1, wd2, wd3;
                xswap16(r0[0], r0[1], wd0, wd2);
                xswap16(r1[0], r1[1], wd1, wd3);
                union { int wd[4]; bf16x8 v; } pu;
                pu.wd[0] = wd0; pu.wd[1] = wd1; pu.wd[2] = wd2; pu.wd[3] = wd3;
                acc[0][ni] = __builtin_amdgcn_mfma_f32_16x16x32_bf16(va0, pu.v, acc[0][ni], 0, 0, 0);
                acc[1][ni] = __builtin_amdgcn_mfma_f32_16x16x32_bf16(va1, pu.v, acc[1][ni], 0, 0, 0);
            }
        }
        if (ch < 8) {
            #pragma unroll
            for (int mi = 0; mi < 4; mi++) { bl[mi] = bln[mi]; bh[mi] = bhn[mi]; }
        }
    }

    // epilogue: d=30 row of O^T is sum(P); divide, write padded [t][h*32+d]
    #pragma unroll
    for (int ni = 0; ni < 4; ni++) {
        float sum = __shfl(acc[1][ni][2], 48 + l15);
        float inv = 1.f / sum;
        int q = wv * 64 + ni * 16 + l15;
        int y = wy * 16 + (q >> 4), x = wx * 16 + (q & 15);
        u16* bp = attn_out + ((long)(y * 256 + x)) * 192 + h * 32;
        *(unsigned*)(bp + lg * 4)     = pk_bf16(acc[0][ni][0] * inv, acc[0][ni][1] * inv);
        *(unsigned*)(bp + lg * 4 + 2) = pk_bf16(acc[0][ni][2] * inv, acc[0][ni][3] * inv);
        if (lg < 3) {
            *(unsigned*)(bp + 16 + lg * 4)     = pk_bf16(acc[1][ni][0] * inv, acc[1][ni][1] * inv);
            *(unsigned*)(bp + 16 + lg * 4 + 2) = pk_bf16(acc[1][ni][2] * inv, acc[1][ni][3] * inv);
        } else {
            *(unsigned*)(bp + 28) = pk_bf16(acc[1][ni][0] * inv, acc[1][ni][1] * inv);
            *(unsigned*)(bp + 30) = 0u;     // dims 30,31 (projT pad rows zero)
        }
    }
}

// ---------------------------------------------------------------------------
extern "C" void kernel_launch(void* const* d_in, const int* in_sizes, int n_in,
                              void* d_out, int out_size, void* d_ws, size_t ws_size,
                              hipStream_t stream)
{
    (void)in_sizes; (void)n_in; (void)out_size; (void)ws_size;
    const float* x      = (const float*)d_in[0];
    const int*   rpi    = (const int*)d_in[1];
    const float* n1w    = (const float*)d_in[2];
    const float* n1b    = (const float*)d_in[3];
    const float* qkv_w  = (const float*)d_in[4];
    const float* qkv_b  = (const float*)d_in[5];
    const float* rpb    = (const float*)d_in[6];
    const float* proj_w = (const float*)d_in[7];
    const float* proj_b = (const float*)d_in[8];
    const float* n2w    = (const float*)d_in[9];
    const float* n2b    = (const float*)d_in[10];
    const float* fc1_w  = (const float*)d_in[11];
    const float* fc1_b  = (const float*)d_in[12];
    const float* fc2_w  = (const float*)d_in[13];
    const float* fc2_b  = (const float*)d_in[14];
    float* out = (float*)d_out;

    char* ws = (char*)d_ws;
    size_t off = 0;
    auto alloc = [&](size_t bytes) -> void* {
        void* p = ws + off; off += (bytes + 511) & ~(size_t)511; return p;
    };
    u16*   xn     = (u16*)alloc(65536ull * 192 * 2);        // ln1 out; ao aliases
    u16*   q_g    = (u16*)alloc(65536ull * 192 * 2);        // [win][h][q][32]
    u16*   K_pad  = (u16*)alloc(6ull * 264 * 264 * 32 * 2); // [h][y][x][32]
    u16*   x2b    = (u16*)alloc(65536ull * 192 * 2);        // bf16 resid stream
    u16*   vP     = (u16*)alloc(6ull * 32 * 264 * 272 * 2); // [h][d][y+4][x+4]
    u16*   bias5  = (u16*)alloc(6ull * 36 * 4 * 4 * 16 * 16 * 2);
    u16*   qkvT   = (u16*)alloc(640ull * 192 * 2);
    u16*   projT  = (u16*)alloc(256ull * 192 * 2);
    u16*   fc1T   = (u16*)alloc(384ull * 192 * 2);
    u16*   fc2T   = (u16*)alloc(256ull * 384 * 2);
    u16*   ao     = xn;    // attn overwrites all 192 cols per token

    prepln_k<<<dim3(28168), dim3(256), 0, stream>>>(x, n1w, n1b, xn,
        qkv_w, proj_w, fc1_w, fc2_w, rpi, rpb,
        qkvT, projT, fc1T, fc2T, bias5, (unsigned*)K_pad, (unsigned*)vP);
    gemm_k<192, 3, 0><<<dim3(512, 3), dim3(256), 0, stream>>>(
        xn, qkvT, qkv_b, (const float*)nullptr, q_g, K_pad, vP);
    attn_k<<<dim3(256, 6), dim3(256), 0, stream>>>(q_g, K_pad, vP, bias5, ao);
    gemm_k<192, 3, 1><<<dim3(512, 1), dim3(256), 0, stream>>>(
        ao, projT, proj_b, x, x2b, nullptr, nullptr);
    mlp_k<<<dim3(1024), dim3(256), 0, stream>>>(
        x2b, fc1T, fc2T, fc1_b, fc2_b, n2w, n2b, out);
}